// Round 10
// baseline (650.561 us; speedup 1.0000x reference)
//
#include <hip/hip_runtime.h>
#include <hip/hip_bf16.h>

// Problem constants (fixed by the reference).
constexpr int N_NODES = 50000;
constexpr int N_REL   = 4;
constexpr int N_EDGES = 800000;
constexpr int DIM     = 128;     // IN_DIM == HID == 128
constexpr int N_CLS   = 16;

constexpr int CHUNK  = 256;
constexpr int NCHUNK = (N_NODES + CHUNK - 1) / CHUNK;  // 196
constexpr int NPART  = N_REL * NCHUNK;                 // 784

// Degree histogram decomposition (round-2 proven; 2-range and packed
// variants both regressed — parallelism beats pass-count here):
// node ranges of 12544 (49 KB LDS), edge tiles of 80000.
constexpr int RNG    = 12544;
constexpr int NRANGE = 4;                      // 4*12544 = 50176 >= 50000
constexpr int DTILE  = 80000;
constexpr int DNT    = N_EDGES / DTILE;        // 10 (exact)

// Gather batching: 8 dst nodes per block (6250 blocks, exact: 6250*8=50000).
constexpr int NPB = 8;
// Per-relation LDS capacity for the staged csr segment (avg 128, sigma~11;
// 512 is a >30-sigma bound; global-read fallback otherwise).
constexpr int CAP = 512;

// Y table padded rows: row N_NODES per relation is a zero sentinel row
// (written once by zero_pad, never touched by the gemm) — gather tail
// loads hit it and contribute 0.
constexpr int N_PAD = 50048;

// fp8 range scale: Y = YS * sout * (x@W); inverse folded into sinF.
constexpr float YSCALE = 32.0f;

typedef __attribute__((ext_vector_type(8))) short short8;
typedef __attribute__((ext_vector_type(4))) float float4v;
typedef __attribute__((ext_vector_type(2))) float floatx2;

// ---- bf16 helpers (manual, round-to-nearest-even) -------------------------
__device__ __forceinline__ unsigned int f2bf_bits(float f) {
  unsigned int u = __float_as_uint(f);
  return (u + 0x7fffu + ((u >> 16) & 1u)) >> 16;
}
__device__ __forceinline__ unsigned int pack2bf(float a, float b) {
  return f2bf_bits(a) | (f2bf_bits(b) << 16);
}
__device__ __forceinline__ float bf_lo(unsigned int u) { return __uint_as_float(u << 16); }
__device__ __forceinline__ float bf_hi(unsigned int u) { return __uint_as_float(u & 0xffff0000u); }

// Column permutation: stored position p <-> logical column (p&7)*16 + (p>>3).
// (Comes from the GEMM epilogue's lane-packed fp8 stores; carried
// consistently through Y -> gather -> X -> next-layer W rows -> head.)
__device__ __forceinline__ int LCOL(int p) { return (p & 7) * 16 + (p >> 3); }

// ---------------------------------------------------------------------------
// K0: degree histograms via block-local LDS ranges + coalesced atomic flush.
// (round-2 structure: 320 blocks, f32 counters — best measured variant)
// ---------------------------------------------------------------------------
__global__ __launch_bounds__(256) void degree_hist(
    const int* __restrict__ src, const int* __restrict__ dst,
    int* __restrict__ cnt_out, int* __restrict__ cnt_in) {
  int b = blockIdx.x;
  int t     = b % DNT;    b /= DNT;
  int range = b % NRANGE; b /= NRANGE;
  int r     = b % N_REL;  b /= N_REL;
  int which = b;          // 0: src->cnt_out, 1: dst->cnt_in
  const int* arr = (which ? dst : src) + (size_t)r * N_EDGES + (size_t)t * DTILE;
  int* cnt = (which ? cnt_in : cnt_out) + r * N_NODES;
  int tid = threadIdx.x;
  __shared__ int h[RNG];
  for (int i = tid; i < RNG; i += 256) h[i] = 0;
  __syncthreads();
  int lo = range * RNG;
  int hi = lo + RNG;
  const int4* a4 = (const int4*)arr;
  for (int i = tid; i < DTILE / 4; i += 256) {
    int4 v = a4[i];
    if (v.x >= lo && v.x < hi) atomicAdd(&h[v.x - lo], 1);
    if (v.y >= lo && v.y < hi) atomicAdd(&h[v.y - lo], 1);
    if (v.z >= lo && v.z < hi) atomicAdd(&h[v.z - lo], 1);
    if (v.w >= lo && v.w < hi) atomicAdd(&h[v.w - lo], 1);
  }
  __syncthreads();
  for (int i = tid; i < RNG; i += 256) {
    int n = lo + i;
    int c = h[i];
    if (n < N_NODES && c) atomicAdd(&cnt[n], c);
  }
}

// ---------------------------------------------------------------------------
// Scan phase A: per-chunk sums of cnt_in.
// ---------------------------------------------------------------------------
__global__ __launch_bounds__(256) void scan_partial(
    const int* __restrict__ cnt_in, int* __restrict__ partial) {
  int b = blockIdx.x;
  int r = b / NCHUNK, c = b % NCHUNK;
  int i = c * CHUNK + threadIdx.x;
  int v = (i < N_NODES) ? cnt_in[r * N_NODES + i] : 0;
#pragma unroll
  for (int off = 1; off < 64; off <<= 1) v += __shfl_xor(v, off, 64);
  __shared__ int ws[4];
  if ((threadIdx.x & 63) == 0) ws[threadIdx.x >> 6] = v;
  __syncthreads();
  if (threadIdx.x == 0) partial[b] = ws[0] + ws[1] + ws[2] + ws[3];
}

// ---------------------------------------------------------------------------
// Scan phase B: 1 block scans NPART partials -> exclusive chunk offsets.
// ---------------------------------------------------------------------------
__global__ __launch_bounds__(1024) void scan_offsets(
    const int* __restrict__ partial, int* __restrict__ chunk_off,
    int* __restrict__ row_ptr) {
  __shared__ int lds[1024];
  __shared__ int sexcl[1024];
  __shared__ int stotal;
  int tid = threadIdx.x;
  int v = (tid < NPART) ? partial[tid] : 0;
  lds[tid] = v;
  __syncthreads();
  for (int off = 1; off < 1024; off <<= 1) {
    int t = (tid >= off) ? lds[tid - off] : 0;
    __syncthreads();
    lds[tid] += t;
    __syncthreads();
  }
  int excl = lds[tid] - v;
  sexcl[tid] = excl;
  if (tid == NPART - 1) stotal = excl + v;
  if (tid < NPART) chunk_off[tid] = excl;
  __syncthreads();
  if (tid < N_REL) {
    int base = sexcl[tid * NCHUNK];
    int next = (tid < N_REL - 1) ? sexcl[(tid + 1) * NCHUNK] : stotal;
    row_ptr[tid * (N_NODES + 1) + N_NODES] = next - base;
  }
}

// ---------------------------------------------------------------------------
// Scan phase C: per-chunk exclusive scan + chunk offset -> row_ptr;
// emits the scatter cursors (copy of row starts) AND (fused) the
// normalization scales + wout.
// ---------------------------------------------------------------------------
__global__ __launch_bounds__(256) void scan_expand(
    const int* __restrict__ cnt_in, const int* __restrict__ chunk_off,
    int* __restrict__ row_ptr, int* __restrict__ cur,
    const int* __restrict__ cnt_out, float* __restrict__ soutF,
    float* __restrict__ sinF, float* __restrict__ wout) {
  int b = blockIdx.x;
  int r = b / NCHUNK, c = b % NCHUNK;
  int tid = threadIdx.x;
  int i = c * CHUNK + tid;
  int v = (i < N_NODES) ? cnt_in[r * N_NODES + i] : 0;
  __shared__ int lds[CHUNK];
  lds[tid] = v;
  __syncthreads();
  for (int off = 1; off < CHUNK; off <<= 1) {
    int t = (tid >= off) ? lds[tid - off] : 0;
    __syncthreads();
    lds[tid] += t;
    __syncthreads();
  }
  int excl = lds[tid] - v;
  int base = chunk_off[b] - chunk_off[r * NCHUNK];
  if (i < N_NODES) {
    int start = base + excl;
    row_ptr[r * (N_NODES + 1) + i] = start;
    cur[r * N_NODES + i] = start;          // scatter cursor init
    int co = cnt_out[r * N_NODES + i];
    soutF[r * N_NODES + i] = YSCALE / sqrtf((float)max(co, 1));
    sinF [r * N_NODES + i] = (1.0f / YSCALE) / sqrtf((float)max(v, 1));
    if (r == 0) {
      wout[i] = (float)(co + cnt_out[N_NODES + i] +
                        cnt_out[2 * N_NODES + i] + cnt_out[3 * N_NODES + i]);
    }
  }
}

// ---------------------------------------------------------------------------
// Direct CSR scatter: one pass over the edges; per-dst position reserved by
// a global atomic on the L2-resident cursor array. Replaces the 2-pass
// bin+sort (the src-sub-ordering it produced buys nothing: gather FETCH is
// at the compulsory-miss floor). Edge order within a node is arbitrary —
// the aggregation is order-invariant.
// ---------------------------------------------------------------------------
__global__ __launch_bounds__(256) void scatter_csr(
    const int* __restrict__ src, const int* __restrict__ dst,
    int* __restrict__ cur, unsigned short* __restrict__ csr) {
  constexpr int E4 = N_EDGES / 4;                 // 200000 int4 per relation
  int idx = blockIdx.x * 256 + threadIdx.x;       // 0 .. N_REL*E4-1
  if (idx >= N_REL * E4) return;
  int r  = idx / E4;
  int e4 = idx - r * E4;
  int4 s4 = ((const int4*)(src + (size_t)r * N_EDGES))[e4];
  int4 d4 = ((const int4*)(dst + (size_t)r * N_EDGES))[e4];
  int* cr = cur + r * N_NODES;
  unsigned short* co = csr + (size_t)r * N_EDGES;
  int p0 = atomicAdd(&cr[d4.x], 1); co[p0] = (unsigned short)s4.x;
  int p1 = atomicAdd(&cr[d4.y], 1); co[p1] = (unsigned short)s4.y;
  int p2 = atomicAdd(&cr[d4.z], 1); co[p2] = (unsigned short)s4.z;
  int p3 = atomicAdd(&cr[d4.w], 1); co[p3] = (unsigned short)s4.w;
}

// ---------------------------------------------------------------------------
// Weight prep (all 3 layers in one launch):
// W[4][128][128] f32 -> Wt[512 cols][128 k] bf16; bsum permuted.
// Layer 1 uses logical k order; layers 2,3 use LCOL-permuted k (their X
// input is the permuted gather output).
// ---------------------------------------------------------------------------
__global__ __launch_bounds__(256) void prep_w3(
    const float* __restrict__ W1, const float* __restrict__ b1,
    const float* __restrict__ W2, const float* __restrict__ b2,
    const float* __restrict__ W3, const float* __restrict__ b3,
    unsigned short* __restrict__ Wt1, float* __restrict__ bs1,
    unsigned short* __restrict__ Wt2, float* __restrict__ bs2,
    unsigned short* __restrict__ Wt3, float* __restrict__ bs3) {
  int set = blockIdx.x >> 8;                // 256 blocks per weight set
  int i   = (blockIdx.x & 255) * 256 + threadIdx.x;
  const float* W = (set == 0) ? W1 : (set == 1) ? W2 : W3;
  const float* b = (set == 0) ? b1 : (set == 1) ? b2 : b3;
  unsigned short* Wt = (set == 0) ? Wt1 : (set == 1) ? Wt2 : Wt3;
  float* bsum = (set == 0) ? bs1 : (set == 1) ? bs2 : bs3;
  int permk = (set != 0);
  if (i < N_REL * DIM * DIM) {
    int col = i >> 7, p = i & 127;
    int k = permk ? LCOL(p) : p;
    int rrel = col >> 7, n = col & 127;
    Wt[i] = (unsigned short)f2bf_bits(W[rrel * DIM * DIM + k * DIM + n]);
  }
  if (i < DIM) {
    int Lp = LCOL(i);
    bsum[i] = b[Lp] + b[DIM + Lp] + b[2 * DIM + Lp] + b[3 * DIM + Lp];
  }
}

// ---------------------------------------------------------------------------
// zero_pad: write the 48 pad rows (incl. the sentinel row N_NODES) of each
// relation's Y table as zeros, ONCE. The gemm never touches these rows, so
// they remain zero across all 3 layers.
// ---------------------------------------------------------------------------
__global__ __launch_bounds__(256) void zero_pad(unsigned char* __restrict__ Yb) {
  constexpr int PER = (N_PAD - N_NODES) * DIM / 16;   // 384 uint4 per relation
  int tid = blockIdx.x * 256 + threadIdx.x;
  int r = tid / PER, k = tid % PER;
  if (r < N_REL) {
    uint4* p = (uint4*)(Yb + (size_t)r * N_PAD * DIM + (size_t)N_NODES * DIM);
    p[k] = make_uint4(0u, 0u, 0u, 0u);
  }
}

// ---------------------------------------------------------------------------
// K5: MFMA GEMM  Y[r][row][p] = fp8( soutF[r][row] * (X[row,:] @ W_r)[LCOL(p)] )
// AF32=1: A is the raw f32 feat (layer 1) — packed to bf16 in the loader.
// AF32=0: A is bf16 [N][128].
// Block = 64 rows x 512 cols; wave w owns relation/quadrant w (128 cols).
// Epilogue is the round-5 proven form: only rows < N_NODES are written
// (pad/sentinel rows are zeroed once by zero_pad, never touched here).
// ---------------------------------------------------------------------------
template <int AF32>
__global__ __launch_bounds__(256) void gemm_y(
    const void* __restrict__ Xv, const unsigned short* __restrict__ Wt,
    const float* __restrict__ soutF, unsigned char* __restrict__ Yb) {
  int tid = threadIdx.x;
  int w   = tid >> 6;           // relation / column quadrant
  int l   = tid & 63;
  int l15 = l & 15, lq = l >> 4;
  int rowbase = blockIdx.x * 64;

  const unsigned short* X = (const unsigned short*)Xv;
  const float*          Xf = (const float*)Xv;

  float4v acc[4][8] = {};
  const unsigned short* Wq = Wt + (size_t)(w * DIM) * DIM;

#pragma unroll
  for (int ks = 0; ks < 4; ++ks) {
    int k0 = ks * 32 + lq * 8;
    short8 bfr[8];
#pragma unroll
    for (int c = 0; c < 8; ++c)
      bfr[c] = *(const short8*)(Wq + (size_t)(c * 16 + l15) * DIM + k0);
#pragma unroll
    for (int i = 0; i < 4; ++i) {
      int rr = rowbase + i * 16 + l15;
      short8 afr;
      if (rr < N_NODES) {
        if (AF32) {
          const float* xp = Xf + (size_t)rr * DIM + k0;
          float4 f0 = *(const float4*)xp;
          float4 f1 = *(const float4*)(xp + 4);
          afr[0] = (short)f2bf_bits(f0.x);
          afr[1] = (short)f2bf_bits(f0.y);
          afr[2] = (short)f2bf_bits(f0.z);
          afr[3] = (short)f2bf_bits(f0.w);
          afr[4] = (short)f2bf_bits(f1.x);
          afr[5] = (short)f2bf_bits(f1.y);
          afr[6] = (short)f2bf_bits(f1.z);
          afr[7] = (short)f2bf_bits(f1.w);
        } else {
          afr = *(const short8*)(X + (size_t)rr * DIM + k0);
        }
      } else {
        afr = (short8)(short)0;
      }
#pragma unroll
      for (int c = 0; c < 8; ++c)
        acc[i][c] = __builtin_amdgcn_mfma_f32_16x16x32_bf16(afr, bfr[c],
                                                            acc[i][c], 0, 0, 0);
    }
  }

  const float* so = soutF + (size_t)w * N_NODES;
  unsigned char* Yq = Yb + (size_t)w * N_PAD * DIM;
#pragma unroll
  for (int i = 0; i < 4; ++i) {
#pragma unroll
    for (int rr = 0; rr < 4; ++rr) {
      int grow = rowbase + i * 16 + lq * 4 + rr;
      if (grow < N_NODES) {
        float sc = so[grow];
        float v0 = acc[i][0][rr] * sc, v1 = acc[i][1][rr] * sc;
        float v2 = acc[i][2][rr] * sc, v3 = acc[i][3][rr] * sc;
        float v4 = acc[i][4][rr] * sc, v5 = acc[i][5][rr] * sc;
        float v6 = acc[i][6][rr] * sc, v7 = acc[i][7][rr] * sc;
        int t0 = __builtin_amdgcn_cvt_pk_fp8_f32(v0, v1, 0, false);
        t0 = __builtin_amdgcn_cvt_pk_fp8_f32(v2, v3, t0, true);
        int t1 = __builtin_amdgcn_cvt_pk_fp8_f32(v4, v5, 0, false);
        t1 = __builtin_amdgcn_cvt_pk_fp8_f32(v6, v7, t1, true);
        uint2 o;
        o.x = (unsigned)t0;
        o.y = (unsigned)t1;
        *(uint2*)(Yq + (size_t)grow * DIM + l15 * 8) = o;
      }
    }
  }
}

// ---------------------------------------------------------------------------
// K4: fused gather, 8 dst nodes per block (round-7 proven: pair-interleave,
// sentinel-padded tails, csr LDS staging, bf16-packed reduce buffer,
// ~12.5 KB LDS -> 8 blocks/CU).
// Epilogue: 32 threads per node: sin, bias, (l2norm + leaky for MODE 1):
//   MODE 1: bf16 X_{l+1}  (next GEMM's A operand)
//   MODE 0: f32  H3       (pool input)
// ---------------------------------------------------------------------------
template <int MODE>
__global__ __launch_bounds__(256) void gather_y(
    const unsigned char* __restrict__ Yb, const unsigned short* __restrict__ csr,
    const int* __restrict__ row_ptr, const float* __restrict__ sinF,
    const float* __restrict__ bsum, void* __restrict__ out) {
  int d0   = blockIdx.x * NPB;
  int r    = threadIdx.x >> 6;
  int lane = threadIdx.x & 63;
  int g    = lane >> 4;   // edge group 0..3
  int l16  = lane & 15;   // covers stored bytes l16*8 .. l16*8+7
  const unsigned short* cs = csr + (size_t)r * N_EDGES;
  const unsigned char*  Yq = Yb + (size_t)r * N_PAD * DIM;

  // lanes 0..8 hold row_ptr[d0..d0+8] (coalesced; d0+NPB <= N_NODES exact)
  int rp = row_ptr[r * (N_NODES + 1) + d0 + min(lane, NPB)];
  int beg0 = __shfl(rp, 0, 64);
  int cnt  = __shfl(rp, NPB, 64) - beg0;

  __shared__ unsigned short scsr[N_REL][CAP];
  __shared__ __align__(16) unsigned int ubuf[N_REL][NPB][66];  // bf16-packed

  int ccap = min(cnt, CAP);
  for (int i = lane; i < ccap; i += 64) scsr[r][i] = cs[beg0 + i];
  // wave-local LDS use only (wave == relation): compiler-inserted lgkmcnt
  // orders the reads below; no block barrier needed before the n-loop.

  auto body = [&](auto CS) {
#pragma unroll 1
    for (int n = 0; n < NPB; n += 2) {
      int bA = __shfl(rp, n, 64),  eA = __shfl(rp, n + 1, 64);
      int bB = eA,                 eB = __shfl(rp, n + 2, 64);
      floatx2 aA[4], aB[4];
#pragma unroll
      for (int j = 0; j < 4; ++j) {
        aA[j] = (floatx2){0.f, 0.f};
        aB[j] = (floatx2){0.f, 0.f};
      }
      int pA = bA, pB = bB;
      while (pA < eA || pB < eB) {
        bool doA = pA < eA, doB = pB < eB;
        uint2 xA[4], xB[4];
        if (doA) {
#pragma unroll
          for (int u = 0; u < 4; ++u) {
            int e = pA + u * 4 + g;
            int se = (e < eA) ? (int)CS(e) : N_NODES;   // zero sentinel row
            xA[u] = *(const uint2*)(Yq + (size_t)se * DIM + l16 * 8);
          }
        }
        if (doB) {
#pragma unroll
          for (int u = 0; u < 4; ++u) {
            int e = pB + u * 4 + g;
            int se = (e < eB) ? (int)CS(e) : N_NODES;
            xB[u] = *(const uint2*)(Yq + (size_t)se * DIM + l16 * 8);
          }
        }
        if (doA) {
#pragma unroll
          for (int u = 0; u < 4; ++u) {
            aA[0] += __builtin_amdgcn_cvt_pk_f32_fp8((int)xA[u].x, false);
            aA[1] += __builtin_amdgcn_cvt_pk_f32_fp8((int)xA[u].x, true);
            aA[2] += __builtin_amdgcn_cvt_pk_f32_fp8((int)xA[u].y, false);
            aA[3] += __builtin_amdgcn_cvt_pk_f32_fp8((int)xA[u].y, true);
          }
          pA += 16;
        }
        if (doB) {
#pragma unroll
          for (int u = 0; u < 4; ++u) {
            aB[0] += __builtin_amdgcn_cvt_pk_f32_fp8((int)xB[u].x, false);
            aB[1] += __builtin_amdgcn_cvt_pk_f32_fp8((int)xB[u].x, true);
            aB[2] += __builtin_amdgcn_cvt_pk_f32_fp8((int)xB[u].y, false);
            aB[3] += __builtin_amdgcn_cvt_pk_f32_fp8((int)xB[u].y, true);
          }
          pB += 16;
        }
      }
      // reduce the 4 edge-groups within the wave (both nodes)
#pragma unroll
      for (int j = 0; j < 4; ++j) {
        aA[j].x += __shfl_xor(aA[j].x, 16, 64);
        aA[j].y += __shfl_xor(aA[j].y, 16, 64);
        aA[j].x += __shfl_xor(aA[j].x, 32, 64);
        aA[j].y += __shfl_xor(aA[j].y, 32, 64);
        aB[j].x += __shfl_xor(aB[j].x, 16, 64);
        aB[j].y += __shfl_xor(aB[j].y, 16, 64);
        aB[j].x += __shfl_xor(aB[j].x, 32, 64);
        aB[j].y += __shfl_xor(aB[j].y, 32, 64);
      }
      if (g < 2) {   // 32 lanes write bf16-packed partials (uint2 each)
        uint2 wA, wB;
        if (g == 0) {
          wA.x = pack2bf(aA[0].x, aA[0].y); wA.y = pack2bf(aA[1].x, aA[1].y);
          wB.x = pack2bf(aB[0].x, aB[0].y); wB.y = pack2bf(aB[1].x, aB[1].y);
        } else {
          wA.x = pack2bf(aA[2].x, aA[2].y); wA.y = pack2bf(aA[3].x, aA[3].y);
          wB.x = pack2bf(aB[2].x, aB[2].y); wB.y = pack2bf(aB[3].x, aB[3].y);
        }
        *(uint2*)&ubuf[r][n][l16 * 4 + g * 2]     = wA;
        *(uint2*)&ubuf[r][n + 1][l16 * 4 + g * 2] = wB;
      }
    }
  };
  if (cnt <= CAP)
    body([&](int e) { return scsr[r][e - beg0]; });
  else
    body([&](int e) { return cs[e]; });
  __syncthreads();

  // Epilogue: 32 threads per node, 4 cols each (uints 2*ln, 2*ln+1).
  int nn = threadIdx.x >> 5;
  int ln = threadIdx.x & 31;
  int d  = d0 + nn;
  float s0 = sinF[d];
  float s1 = sinF[N_NODES + d];
  float s2 = sinF[2 * N_NODES + d];
  float s3 = sinF[3 * N_NODES + d];
  uint2 u0 = *(const uint2*)&ubuf[0][nn][ln * 2];
  uint2 u1 = *(const uint2*)&ubuf[1][nn][ln * 2];
  uint2 u2 = *(const uint2*)&ubuf[2][nn][ln * 2];
  uint2 u3 = *(const uint2*)&ubuf[3][nn][ln * 2];
  float4 bs = *(const float4*)&bsum[ln * 4];
  float v0 = s0 * bf_lo(u0.x) + s1 * bf_lo(u1.x) + s2 * bf_lo(u2.x) +
             s3 * bf_lo(u3.x) + bs.x;
  float v1 = s0 * bf_hi(u0.x) + s1 * bf_hi(u1.x) + s2 * bf_hi(u2.x) +
             s3 * bf_hi(u3.x) + bs.y;
  float v2 = s0 * bf_lo(u0.y) + s1 * bf_lo(u1.y) + s2 * bf_lo(u2.y) +
             s3 * bf_lo(u3.y) + bs.z;
  float v3 = s0 * bf_hi(u0.y) + s1 * bf_hi(u1.y) + s2 * bf_hi(u2.y) +
             s3 * bf_hi(u3.y) + bs.w;
  if (MODE == 1) {
    float ss = v0 * v0 + v1 * v1 + v2 * v2 + v3 * v3;
    ss += __shfl_xor(ss, 1, 32);
    ss += __shfl_xor(ss, 2, 32);
    ss += __shfl_xor(ss, 4, 32);
    ss += __shfl_xor(ss, 8, 32);
    ss += __shfl_xor(ss, 16, 32);
    float sc = 1.0f / fmaxf(sqrtf(ss), 1e-12f);
    v0 *= sc; v1 *= sc; v2 *= sc; v3 *= sc;
    v0 = v0 > 0.f ? v0 : 0.01f * v0;
    v1 = v1 > 0.f ? v1 : 0.01f * v1;
    v2 = v2 > 0.f ? v2 : 0.01f * v2;
    v3 = v3 > 0.f ? v3 : 0.01f * v3;
    uint2 o;
    o.x = pack2bf(v0, v1);
    o.y = pack2bf(v2, v3);
    *(uint2*)((unsigned short*)out + (size_t)d * DIM + ln * 4) = o;
  } else {
    float4 o = make_float4(v0, v1, v2, v3);
    *(float4*)((float*)out + (size_t)d * DIM + ln * 4) = o;
  }
}

// ---------------------------------------------------------------------------
// K6: hg = sum_v wout[v] * h3[v]   (h3 columns are LCOL-permuted; fine)
// ---------------------------------------------------------------------------
__global__ __launch_bounds__(256) void pool_kernel(
    const float* __restrict__ h, const float* __restrict__ wout,
    float* __restrict__ hg) {
  int gw   = blockIdx.x * 4 + (threadIdx.x >> 6);
  int lane = threadIdx.x & 63;
  int nw   = gridDim.x * 4;
  float ax = 0.0f, ay = 0.0f;
  for (int v = gw; v < N_NODES; v += nw) {
    float w = wout[v];
    float2 hv = *(const float2*)(h + (size_t)v * DIM + lane * 2);
    ax = fmaf(w, hv.x, ax);
    ay = fmaf(w, hv.y, ay);
  }
  atomicAdd(&hg[lane * 2],     ax);
  atomicAdd(&hg[lane * 2 + 1], ay);
}

// ---------------------------------------------------------------------------
// K7: head  out = sigmoid( (hg/N) @ Wlin + blin ); hg is LCOL-permuted.
// ---------------------------------------------------------------------------
__global__ void head_kernel(const float* __restrict__ hg,
                            const float* __restrict__ Wlin,
                            const float* __restrict__ blin,
                            float* __restrict__ out) {
  int j = threadIdx.x;
  if (j < N_CLS) {
    float s = blin[j];
    const float invN = 1.0f / (float)N_NODES;
#pragma unroll 16
    for (int k = 0; k < DIM; ++k) {
      int Lk = (k & 7) * 16 + (k >> 3);
      s = fmaf(hg[k] * invN, Wlin[Lk * N_CLS + j], s);
    }
    out[j] = 1.0f / (1.0f + expf(-s));
  }
}

__global__ void fail_kernel(float* out) {
  int i = threadIdx.x;
  if (i < N_CLS) out[i] = 1e30f;
}

// ---------------------------------------------------------------------------
extern "C" void kernel_launch(void* const* d_in, const int* in_sizes, int n_in,
                              void* d_out, int out_size, void* d_ws, size_t ws_size,
                              hipStream_t stream) {
  const float* feat = (const float*)d_in[0];
  const int*   src  = (const int*)  d_in[1];
  const int*   dst  = (const int*)  d_in[2];
  const float* W1   = (const float*)d_in[3];
  const float* b1   = (const float*)d_in[4];
  const float* W2   = (const float*)d_in[5];
  const float* b2   = (const float*)d_in[6];
  const float* W3   = (const float*)d_in[7];
  const float* b3   = (const float*)d_in[8];
  const float* Wlin = (const float*)d_in[9];
  const float* blin = (const float*)d_in[10];
  float* out = (float*)d_out;

  char* base = (char*)d_ws;
  size_t off = 0;
  auto alloc = [&](size_t bytes) -> void* {
    void* q = base + off;
    off = (off + bytes + 255) & ~(size_t)255;
    return q;
  };
  int*   cnt_out  = (int*)  alloc((size_t)N_REL * N_NODES * 4);
  int*   cnt_in   = (int*)  alloc((size_t)N_REL * N_NODES * 4);
  int*   row_ptr  = (int*)  alloc((size_t)N_REL * (N_NODES + 1) * 4);
  float* soutF    = (float*)alloc((size_t)N_REL * N_NODES * 4);
  float* sinF     = (float*)alloc((size_t)N_REL * N_NODES * 4);
  float* wout     = (float*)alloc((size_t)N_NODES * 4);
  float* hg       = (float*)alloc((size_t)DIM * 4);
  int*   partial  = (int*)  alloc((size_t)NPART * 4);
  int*   chunkoff = (int*)  alloc((size_t)NPART * 4);
  int*   cur      = (int*)  alloc((size_t)N_REL * N_NODES * 4);
  unsigned short* csr    = (unsigned short*)alloc((size_t)N_REL * N_EDGES * 2);
  unsigned char*  Yb     = (unsigned char*) alloc((size_t)N_REL * N_PAD * DIM);
  unsigned short* X1     = (unsigned short*)alloc((size_t)N_NODES * DIM * 2);
  unsigned short* X2     = (unsigned short*)alloc((size_t)N_NODES * DIM * 2);
  float* H3       = (float*)alloc((size_t)N_NODES * DIM * 4);
  unsigned short* Wt1 = (unsigned short*)alloc((size_t)N_REL * DIM * DIM * 2);
  unsigned short* Wt2 = (unsigned short*)alloc((size_t)N_REL * DIM * DIM * 2);
  unsigned short* Wt3 = (unsigned short*)alloc((size_t)N_REL * DIM * DIM * 2);
  float* bs1 = (float*)alloc(DIM * 4);
  float* bs2 = (float*)alloc(DIM * 4);
  float* bs3 = (float*)alloc(DIM * 4);

  if (off > ws_size) {  // unambiguous sentinel instead of OOB writes
    fail_kernel<<<1, 64, 0, stream>>>(out);
    return;
  }

  hipMemsetAsync(cnt_out, 0, (size_t)2 * N_REL * N_NODES * 4, stream);
  hipMemsetAsync(hg, 0, DIM * 4, stream);

  // CSR build: degree (LDS hist) -> row_ptr(+cursors+scales) -> direct scatter
  degree_hist  <<<2 * N_REL * NRANGE * DNT, 256, 0, stream>>>(src, dst, cnt_out, cnt_in);
  scan_partial <<<NPART, 256, 0, stream>>>(cnt_in, partial);
  scan_offsets <<<1, 1024, 0, stream>>>(partial, chunkoff, row_ptr);
  scan_expand  <<<NPART, 256, 0, stream>>>(cnt_in, chunkoff, row_ptr, cur,
                                           cnt_out, soutF, sinF, wout);
  scatter_csr  <<<(N_REL * N_EDGES / 4 + 255) / 256, 256, 0, stream>>>(
      src, dst, cur, csr);

  // Weight prep (single launch, 3 sets) + one-time sentinel-row zeroing
  prep_w3<<<3 * 256, 256, 0, stream>>>(W1, b1, W2, b2, W3, b3,
                                       Wt1, bs1, Wt2, bs2, Wt3, bs3);
  zero_pad<<<6, 256, 0, stream>>>(Yb);

  int gemm_blocks = N_PAD / 64;                  // 782 (last block: A rows 0)
  int gath_blocks = (N_NODES + NPB - 1) / NPB;   // 6250, exact

  // Layer 1: transform-then-aggregate (GEMM reads f32 feat directly)
  gemm_y<1>  <<<gemm_blocks, 256, 0, stream>>>(feat, Wt1, soutF, Yb);
  gather_y<1><<<gath_blocks, 256, 0, stream>>>(Yb, csr, row_ptr, sinF, bs1, X1);
  // Layer 2
  gemm_y<0>  <<<gemm_blocks, 256, 0, stream>>>(X1, Wt2, soutF, Yb);
  gather_y<1><<<gath_blocks, 256, 0, stream>>>(Yb, csr, row_ptr, sinF, bs2, X2);
  // Layer 3 (no norm/act, f32 out)
  gemm_y<0>  <<<gemm_blocks, 256, 0, stream>>>(X2, Wt3, soutF, Yb);
  gather_y<0><<<gath_blocks, 256, 0, stream>>>(Yb, csr, row_ptr, sinF, bs3, H3);

  // Pool + head
  pool_kernel<<<256, 256, 0, stream>>>(H3, wout, hg);
  head_kernel<<<1, 64, 0, stream>>>(hg, Wlin, blin, out);
}

// Round 11
// 486.839 us; speedup vs baseline: 1.3363x; 1.3363x over previous
//
#include <hip/hip_runtime.h>
#include <hip/hip_bf16.h>

// Problem constants (fixed by the reference).
constexpr int N_NODES = 50000;
constexpr int N_REL   = 4;
constexpr int N_EDGES = 800000;
constexpr int DIM     = 128;     // IN_DIM == HID == 128
constexpr int N_CLS   = 16;

constexpr int CHUNK  = 256;
constexpr int NCHUNK = (N_NODES + CHUNK - 1) / CHUNK;  // 196
constexpr int NPART  = N_REL * NCHUNK;                 // 784

// Coarse bins: 256 dst nodes per bin (dst>>8).  NCBR == NCHUNK by design.
constexpr int NCBR  = (N_NODES + 255) / 256;   // 196
constexpr int NCB   = N_REL * NCBR;            // 784
constexpr int TILE  = 8000;                    // edges per pass1 block
constexpr int TPR   = N_EDGES / TILE;          // 100 (exact)
constexpr int MAXB  = 6144;                    // bin capacity for LDS sort path

// Degree histogram decomposition (round-2 proven; 2-range / packed / direct-
// scatter variants all regressed — parallelism + coalesced writes win):
// node ranges of 12544 (49 KB LDS), edge tiles of 80000.
constexpr int RNG    = 12544;
constexpr int NRANGE = 4;                      // 4*12544 = 50176 >= 50000
constexpr int DTILE  = 80000;
constexpr int DNT    = N_EDGES / DTILE;        // 10 (exact)

// Gather batching: 8 dst nodes per block (6250 blocks, exact: 6250*8=50000).
constexpr int NPB = 8;
// Per-relation LDS capacity for the staged csr segment (avg 128, sigma~11;
// 512 is a >30-sigma bound; global-read fallback otherwise).
constexpr int CAP = 512;

// Y table padded rows: row N_NODES per relation is a zero sentinel row
// (written once by zero_pad, never touched by the gemm) — gather tail
// loads hit it and contribute 0.
constexpr int N_PAD = 50048;

// fp8 range scale: Y = YS * sout * (x@W); inverse folded into sinF.
constexpr float YSCALE = 32.0f;

typedef __attribute__((ext_vector_type(8))) short short8;
typedef __attribute__((ext_vector_type(4))) float float4v;
typedef __attribute__((ext_vector_type(2))) float floatx2;

// ---- bf16 helpers (manual, round-to-nearest-even) -------------------------
__device__ __forceinline__ unsigned int f2bf_bits(float f) {
  unsigned int u = __float_as_uint(f);
  return (u + 0x7fffu + ((u >> 16) & 1u)) >> 16;
}
__device__ __forceinline__ unsigned int pack2bf(float a, float b) {
  return f2bf_bits(a) | (f2bf_bits(b) << 16);
}
__device__ __forceinline__ float bf_lo(unsigned int u) { return __uint_as_float(u << 16); }
__device__ __forceinline__ float bf_hi(unsigned int u) { return __uint_as_float(u & 0xffff0000u); }

// Column permutation: stored position p <-> logical column (p&7)*16 + (p>>3).
// (Comes from the GEMM epilogue's lane-packed fp8 stores; carried
// consistently through Y -> gather -> X -> next-layer W rows -> head.)
__device__ __forceinline__ int LCOL(int p) { return (p & 7) * 16 + (p >> 3); }

// ---------------------------------------------------------------------------
// K0: degree histograms via block-local LDS ranges + coalesced atomic flush.
// (round-2 structure: 320 blocks, f32 counters — best measured variant)
// ---------------------------------------------------------------------------
__global__ __launch_bounds__(256) void degree_hist(
    const int* __restrict__ src, const int* __restrict__ dst,
    int* __restrict__ cnt_out, int* __restrict__ cnt_in) {
  int b = blockIdx.x;
  int t     = b % DNT;    b /= DNT;
  int range = b % NRANGE; b /= NRANGE;
  int r     = b % N_REL;  b /= N_REL;
  int which = b;          // 0: src->cnt_out, 1: dst->cnt_in
  const int* arr = (which ? dst : src) + (size_t)r * N_EDGES + (size_t)t * DTILE;
  int* cnt = (which ? cnt_in : cnt_out) + r * N_NODES;
  int tid = threadIdx.x;
  __shared__ int h[RNG];
  for (int i = tid; i < RNG; i += 256) h[i] = 0;
  __syncthreads();
  int lo = range * RNG;
  int hi = lo + RNG;
  const int4* a4 = (const int4*)arr;
  for (int i = tid; i < DTILE / 4; i += 256) {
    int4 v = a4[i];
    if (v.x >= lo && v.x < hi) atomicAdd(&h[v.x - lo], 1);
    if (v.y >= lo && v.y < hi) atomicAdd(&h[v.y - lo], 1);
    if (v.z >= lo && v.z < hi) atomicAdd(&h[v.z - lo], 1);
    if (v.w >= lo && v.w < hi) atomicAdd(&h[v.w - lo], 1);
  }
  __syncthreads();
  for (int i = tid; i < RNG; i += 256) {
    int n = lo + i;
    int c = h[i];
    if (n < N_NODES && c) atomicAdd(&cnt[n], c);
  }
}

// ---------------------------------------------------------------------------
// Scan phase A: per-chunk sums of cnt_in.
// ---------------------------------------------------------------------------
__global__ __launch_bounds__(256) void scan_partial(
    const int* __restrict__ cnt_in, int* __restrict__ partial) {
  int b = blockIdx.x;
  int r = b / NCHUNK, c = b % NCHUNK;
  int i = c * CHUNK + threadIdx.x;
  int v = (i < N_NODES) ? cnt_in[r * N_NODES + i] : 0;
#pragma unroll
  for (int off = 1; off < 64; off <<= 1) v += __shfl_xor(v, off, 64);
  __shared__ int ws[4];
  if ((threadIdx.x & 63) == 0) ws[threadIdx.x >> 6] = v;
  __syncthreads();
  if (threadIdx.x == 0) partial[b] = ws[0] + ws[1] + ws[2] + ws[3];
}

// ---------------------------------------------------------------------------
// Scan phase B: 1 block scans NPART partials -> exclusive chunk offsets.
// ---------------------------------------------------------------------------
__global__ __launch_bounds__(1024) void scan_offsets(
    const int* __restrict__ partial, int* __restrict__ chunk_off,
    int* __restrict__ row_ptr) {
  __shared__ int lds[1024];
  __shared__ int sexcl[1024];
  __shared__ int stotal;
  int tid = threadIdx.x;
  int v = (tid < NPART) ? partial[tid] : 0;
  lds[tid] = v;
  __syncthreads();
  for (int off = 1; off < 1024; off <<= 1) {
    int t = (tid >= off) ? lds[tid - off] : 0;
    __syncthreads();
    lds[tid] += t;
    __syncthreads();
  }
  int excl = lds[tid] - v;
  sexcl[tid] = excl;
  if (tid == NPART - 1) stotal = excl + v;
  if (tid < NPART) chunk_off[tid] = excl;
  __syncthreads();
  if (tid < N_REL) {
    int base = sexcl[tid * NCHUNK];
    int next = (tid < N_REL - 1) ? sexcl[(tid + 1) * NCHUNK] : stotal;
    row_ptr[tid * (N_NODES + 1) + N_NODES] = next - base;
  }
}

// ---------------------------------------------------------------------------
// Scan phase C: per-chunk exclusive scan + chunk offset -> row_ptr;
// emits coarse-bin cursors AND (fused) the normalization scales + wout.
// ---------------------------------------------------------------------------
__global__ __launch_bounds__(256) void scan_expand(
    const int* __restrict__ cnt_in, const int* __restrict__ chunk_off,
    int* __restrict__ row_ptr, int* __restrict__ cbcur,
    const int* __restrict__ cnt_out, float* __restrict__ soutF,
    float* __restrict__ sinF, float* __restrict__ wout) {
  int b = blockIdx.x;
  int r = b / NCHUNK, c = b % NCHUNK;
  int tid = threadIdx.x;
  int i = c * CHUNK + tid;
  int v = (i < N_NODES) ? cnt_in[r * N_NODES + i] : 0;
  __shared__ int lds[CHUNK];
  lds[tid] = v;
  __syncthreads();
  for (int off = 1; off < CHUNK; off <<= 1) {
    int t = (tid >= off) ? lds[tid - off] : 0;
    __syncthreads();
    lds[tid] += t;
    __syncthreads();
  }
  int excl = lds[tid] - v;
  int base = chunk_off[b] - chunk_off[r * NCHUNK];
  if (i < N_NODES) {
    row_ptr[r * (N_NODES + 1) + i] = base + excl;
    int co = cnt_out[r * N_NODES + i];
    soutF[r * N_NODES + i] = YSCALE / sqrtf((float)max(co, 1));
    sinF [r * N_NODES + i] = (1.0f / YSCALE) / sqrtf((float)max(v, 1));
    if (r == 0) {
      wout[i] = (float)(co + cnt_out[N_NODES + i] +
                        cnt_out[2 * N_NODES + i] + cnt_out[3 * N_NODES + i]);
    }
  }
  if (tid == 0) cbcur[r * NCBR + c] = base;   // bin start == chunk start
}

// ---------------------------------------------------------------------------
// Pass 1: per-block LDS binning into 196 coarse bins; one global atomic per
// (block,bin) reserves a contiguous chunk. Payload: src<<8 | dst&255.
// (LDS-staged, coalesced chunk writes — direct global scatter costs ~32x
// write amplification across non-coherent XCD L2s, measured round 9.)
// ---------------------------------------------------------------------------
__global__ __launch_bounds__(256) void pass1_bin(
    const int* __restrict__ src, const int* __restrict__ dst,
    int* __restrict__ cbcur, unsigned int* __restrict__ binned) {
  int b = blockIdx.x;
  int r = b / TPR, t = b % TPR;
  const int* sp = src + (size_t)r * N_EDGES + t * TILE;
  const int* dp = dst + (size_t)r * N_EDGES + t * TILE;
  unsigned int* outp = binned + (size_t)r * N_EDGES;
  int tid = threadIdx.x;
  __shared__ int hist[NCBR];
  __shared__ int scanb[256];
  __shared__ int gbase[NCBR];
  __shared__ int lcur[NCBR];
  for (int i = tid; i < NCBR; i += 256) hist[i] = 0;
  __syncthreads();
  for (int i = tid; i < TILE; i += 256) atomicAdd(&hist[dp[i] >> 8], 1);
  __syncthreads();
  int v = (tid < NCBR) ? hist[tid] : 0;
  scanb[tid] = v;
  __syncthreads();
  for (int off = 1; off < 256; off <<= 1) {
    int tv = (tid >= off) ? scanb[tid - off] : 0;
    __syncthreads();
    scanb[tid] += tv;
    __syncthreads();
  }
  if (tid < NCBR) {
    int excl = scanb[tid] - v;
    gbase[tid] = atomicAdd(&cbcur[r * NCBR + tid], v) - excl;
    lcur[tid] = excl;
  }
  __syncthreads();
  for (int i = tid; i < TILE; i += 256) {
    int d = dp[i];
    int s = sp[i];
    int cb = d >> 8;
    int lp = atomicAdd(&lcur[cb], 1);
    outp[gbase[cb] + lp] = ((unsigned)s << 8) | (unsigned)(d & 255);
  }
}

// ---------------------------------------------------------------------------
// Pass 2: one block per coarse bin; LDS counting sort by dst&255 ONLY
// (256 keys — the old src>>12 sub-order bought nothing: gather FETCH is at
// the compulsory-miss floor). 1 KB hist, one key per thread, ~14.8 KB LDS.
// ---------------------------------------------------------------------------
__global__ __launch_bounds__(256) void pass2_sort(
    const unsigned int* __restrict__ binned, const int* __restrict__ row_ptr,
    unsigned short* __restrict__ csr) {
  int b = blockIdx.x;
  int r = b / NCBR, c = b % NCBR;
  int node0 = c * 256;
  int node1 = min(node0 + 256, N_NODES);
  int start = row_ptr[r * (N_NODES + 1) + node0];
  int endv  = row_ptr[r * (N_NODES + 1) + node1];
  int count = endv - start;
  const unsigned int* bp = binned + (size_t)r * N_EDGES + start;
  unsigned short* outg = csr + (size_t)r * N_EDGES + start;
  int tid = threadIdx.x;
  __shared__ int hist[256];
  __shared__ int scanb[256];
  __shared__ unsigned short outb[MAXB];
  hist[tid] = 0;
  __syncthreads();
  for (int i = tid; i < count; i += 256) atomicAdd(&hist[bp[i] & 255u], 1);
  __syncthreads();
  int v = hist[tid];
  scanb[tid] = v;
  __syncthreads();
  for (int off = 1; off < 256; off <<= 1) {
    int tv = (tid >= off) ? scanb[tid - off] : 0;
    __syncthreads();
    scanb[tid] += tv;
    __syncthreads();
  }
  hist[tid] = scanb[tid] - v;          // exclusive start -> running cursor
  __syncthreads();
  if (count <= MAXB) {
    for (int i = tid; i < count; i += 256) {
      unsigned int p = bp[i];
      int pos = atomicAdd(&hist[p & 255u], 1);
      outb[pos] = (unsigned short)(p >> 8);
    }
    __syncthreads();
    for (int i = tid; i < count; i += 256) outg[i] = outb[i];
  } else {
    for (int i = tid; i < count; i += 256) {
      unsigned int p = bp[i];
      int pos = atomicAdd(&hist[p & 255u], 1);
      outg[pos] = (unsigned short)(p >> 8);
    }
  }
}

// ---------------------------------------------------------------------------
// Weight prep (all 3 layers in one launch):
// W[4][128][128] f32 -> Wt[512 cols][128 k] bf16; bsum permuted.
// Layer 1 uses logical k order; layers 2,3 use LCOL-permuted k (their X
// input is the permuted gather output).
// ---------------------------------------------------------------------------
__global__ __launch_bounds__(256) void prep_w3(
    const float* __restrict__ W1, const float* __restrict__ b1,
    const float* __restrict__ W2, const float* __restrict__ b2,
    const float* __restrict__ W3, const float* __restrict__ b3,
    unsigned short* __restrict__ Wt1, float* __restrict__ bs1,
    unsigned short* __restrict__ Wt2, float* __restrict__ bs2,
    unsigned short* __restrict__ Wt3, float* __restrict__ bs3) {
  int set = blockIdx.x >> 8;                // 256 blocks per weight set
  int i   = (blockIdx.x & 255) * 256 + threadIdx.x;
  const float* W = (set == 0) ? W1 : (set == 1) ? W2 : W3;
  const float* b = (set == 0) ? b1 : (set == 1) ? b2 : b3;
  unsigned short* Wt = (set == 0) ? Wt1 : (set == 1) ? Wt2 : Wt3;
  float* bsum = (set == 0) ? bs1 : (set == 1) ? bs2 : bs3;
  int permk = (set != 0);
  if (i < N_REL * DIM * DIM) {
    int col = i >> 7, p = i & 127;
    int k = permk ? LCOL(p) : p;
    int rrel = col >> 7, n = col & 127;
    Wt[i] = (unsigned short)f2bf_bits(W[rrel * DIM * DIM + k * DIM + n]);
  }
  if (i < DIM) {
    int Lp = LCOL(i);
    bsum[i] = b[Lp] + b[DIM + Lp] + b[2 * DIM + Lp] + b[3 * DIM + Lp];
  }
}

// ---------------------------------------------------------------------------
// zero_pad: write the 48 pad rows (incl. the sentinel row N_NODES) of each
// relation's Y table as zeros, ONCE. The gemm never touches these rows, so
// they remain zero across all 3 layers.
// ---------------------------------------------------------------------------
__global__ __launch_bounds__(256) void zero_pad(unsigned char* __restrict__ Yb) {
  constexpr int PER = (N_PAD - N_NODES) * DIM / 16;   // 384 uint4 per relation
  int tid = blockIdx.x * 256 + threadIdx.x;
  int r = tid / PER, k = tid % PER;
  if (r < N_REL) {
    uint4* p = (uint4*)(Yb + (size_t)r * N_PAD * DIM + (size_t)N_NODES * DIM);
    p[k] = make_uint4(0u, 0u, 0u, 0u);
  }
}

// ---------------------------------------------------------------------------
// K5: MFMA GEMM  Y[r][row][p] = fp8( soutF[r][row] * (X[row,:] @ W_r)[LCOL(p)] )
// AF32=1: A is the raw f32 feat (layer 1) — packed to bf16 in the loader.
// AF32=0: A is bf16 [N][128].
// Block = 64 rows x 512 cols; wave w owns relation/quadrant w (128 cols).
// Epilogue is the round-5 proven form: only rows < N_NODES are written
// (pad/sentinel rows are zeroed once by zero_pad, never touched here).
// ---------------------------------------------------------------------------
template <int AF32>
__global__ __launch_bounds__(256) void gemm_y(
    const void* __restrict__ Xv, const unsigned short* __restrict__ Wt,
    const float* __restrict__ soutF, unsigned char* __restrict__ Yb) {
  int tid = threadIdx.x;
  int w   = tid >> 6;           // relation / column quadrant
  int l   = tid & 63;
  int l15 = l & 15, lq = l >> 4;
  int rowbase = blockIdx.x * 64;

  const unsigned short* X = (const unsigned short*)Xv;
  const float*          Xf = (const float*)Xv;

  float4v acc[4][8] = {};
  const unsigned short* Wq = Wt + (size_t)(w * DIM) * DIM;

#pragma unroll
  for (int ks = 0; ks < 4; ++ks) {
    int k0 = ks * 32 + lq * 8;
    short8 bfr[8];
#pragma unroll
    for (int c = 0; c < 8; ++c)
      bfr[c] = *(const short8*)(Wq + (size_t)(c * 16 + l15) * DIM + k0);
#pragma unroll
    for (int i = 0; i < 4; ++i) {
      int rr = rowbase + i * 16 + l15;
      short8 afr;
      if (rr < N_NODES) {
        if (AF32) {
          const float* xp = Xf + (size_t)rr * DIM + k0;
          float4 f0 = *(const float4*)xp;
          float4 f1 = *(const float4*)(xp + 4);
          afr[0] = (short)f2bf_bits(f0.x);
          afr[1] = (short)f2bf_bits(f0.y);
          afr[2] = (short)f2bf_bits(f0.z);
          afr[3] = (short)f2bf_bits(f0.w);
          afr[4] = (short)f2bf_bits(f1.x);
          afr[5] = (short)f2bf_bits(f1.y);
          afr[6] = (short)f2bf_bits(f1.z);
          afr[7] = (short)f2bf_bits(f1.w);
        } else {
          afr = *(const short8*)(X + (size_t)rr * DIM + k0);
        }
      } else {
        afr = (short8)(short)0;
      }
#pragma unroll
      for (int c = 0; c < 8; ++c)
        acc[i][c] = __builtin_amdgcn_mfma_f32_16x16x32_bf16(afr, bfr[c],
                                                            acc[i][c], 0, 0, 0);
    }
  }

  const float* so = soutF + (size_t)w * N_NODES;
  unsigned char* Yq = Yb + (size_t)w * N_PAD * DIM;
#pragma unroll
  for (int i = 0; i < 4; ++i) {
#pragma unroll
    for (int rr = 0; rr < 4; ++rr) {
      int grow = rowbase + i * 16 + lq * 4 + rr;
      if (grow < N_NODES) {
        float sc = so[grow];
        float v0 = acc[i][0][rr] * sc, v1 = acc[i][1][rr] * sc;
        float v2 = acc[i][2][rr] * sc, v3 = acc[i][3][rr] * sc;
        float v4 = acc[i][4][rr] * sc, v5 = acc[i][5][rr] * sc;
        float v6 = acc[i][6][rr] * sc, v7 = acc[i][7][rr] * sc;
        int t0 = __builtin_amdgcn_cvt_pk_fp8_f32(v0, v1, 0, false);
        t0 = __builtin_amdgcn_cvt_pk_fp8_f32(v2, v3, t0, true);
        int t1 = __builtin_amdgcn_cvt_pk_fp8_f32(v4, v5, 0, false);
        t1 = __builtin_amdgcn_cvt_pk_fp8_f32(v6, v7, t1, true);
        uint2 o;
        o.x = (unsigned)t0;
        o.y = (unsigned)t1;
        *(uint2*)(Yq + (size_t)grow * DIM + l15 * 8) = o;
      }
    }
  }
}

// ---------------------------------------------------------------------------
// K4: fused gather, 8 dst nodes per block (round-7 proven: pair-interleave,
// sentinel-padded tails, csr LDS staging, bf16-packed reduce buffer,
// ~12.5 KB LDS -> 8 blocks/CU).
// Epilogue: 32 threads per node: sin, bias, (l2norm + leaky for MODE 1):
//   MODE 1: bf16 X_{l+1}  (next GEMM's A operand)
//   MODE 0: f32  H3       (pool input)
// ---------------------------------------------------------------------------
template <int MODE>
__global__ __launch_bounds__(256) void gather_y(
    const unsigned char* __restrict__ Yb, const unsigned short* __restrict__ csr,
    const int* __restrict__ row_ptr, const float* __restrict__ sinF,
    const float* __restrict__ bsum, void* __restrict__ out) {
  int d0   = blockIdx.x * NPB;
  int r    = threadIdx.x >> 6;
  int lane = threadIdx.x & 63;
  int g    = lane >> 4;   // edge group 0..3
  int l16  = lane & 15;   // covers stored bytes l16*8 .. l16*8+7
  const unsigned short* cs = csr + (size_t)r * N_EDGES;
  const unsigned char*  Yq = Yb + (size_t)r * N_PAD * DIM;

  // lanes 0..8 hold row_ptr[d0..d0+8] (coalesced; d0+NPB <= N_NODES exact)
  int rp = row_ptr[r * (N_NODES + 1) + d0 + min(lane, NPB)];
  int beg0 = __shfl(rp, 0, 64);
  int cnt  = __shfl(rp, NPB, 64) - beg0;

  __shared__ unsigned short scsr[N_REL][CAP];
  __shared__ __align__(16) unsigned int ubuf[N_REL][NPB][66];  // bf16-packed

  int ccap = min(cnt, CAP);
  for (int i = lane; i < ccap; i += 64) scsr[r][i] = cs[beg0 + i];
  // wave-local LDS use only (wave == relation): compiler-inserted lgkmcnt
  // orders the reads below; no block barrier needed before the n-loop.

  auto body = [&](auto CS) {
#pragma unroll 1
    for (int n = 0; n < NPB; n += 2) {
      int bA = __shfl(rp, n, 64),  eA = __shfl(rp, n + 1, 64);
      int bB = eA,                 eB = __shfl(rp, n + 2, 64);
      floatx2 aA[4], aB[4];
#pragma unroll
      for (int j = 0; j < 4; ++j) {
        aA[j] = (floatx2){0.f, 0.f};
        aB[j] = (floatx2){0.f, 0.f};
      }
      int pA = bA, pB = bB;
      while (pA < eA || pB < eB) {
        bool doA = pA < eA, doB = pB < eB;
        uint2 xA[4], xB[4];
        if (doA) {
#pragma unroll
          for (int u = 0; u < 4; ++u) {
            int e = pA + u * 4 + g;
            int se = (e < eA) ? (int)CS(e) : N_NODES;   // zero sentinel row
            xA[u] = *(const uint2*)(Yq + (size_t)se * DIM + l16 * 8);
          }
        }
        if (doB) {
#pragma unroll
          for (int u = 0; u < 4; ++u) {
            int e = pB + u * 4 + g;
            int se = (e < eB) ? (int)CS(e) : N_NODES;
            xB[u] = *(const uint2*)(Yq + (size_t)se * DIM + l16 * 8);
          }
        }
        if (doA) {
#pragma unroll
          for (int u = 0; u < 4; ++u) {
            aA[0] += __builtin_amdgcn_cvt_pk_f32_fp8((int)xA[u].x, false);
            aA[1] += __builtin_amdgcn_cvt_pk_f32_fp8((int)xA[u].x, true);
            aA[2] += __builtin_amdgcn_cvt_pk_f32_fp8((int)xA[u].y, false);
            aA[3] += __builtin_amdgcn_cvt_pk_f32_fp8((int)xA[u].y, true);
          }
          pA += 16;
        }
        if (doB) {
#pragma unroll
          for (int u = 0; u < 4; ++u) {
            aB[0] += __builtin_amdgcn_cvt_pk_f32_fp8((int)xB[u].x, false);
            aB[1] += __builtin_amdgcn_cvt_pk_f32_fp8((int)xB[u].x, true);
            aB[2] += __builtin_amdgcn_cvt_pk_f32_fp8((int)xB[u].y, false);
            aB[3] += __builtin_amdgcn_cvt_pk_f32_fp8((int)xB[u].y, true);
          }
          pB += 16;
        }
      }
      // reduce the 4 edge-groups within the wave (both nodes)
#pragma unroll
      for (int j = 0; j < 4; ++j) {
        aA[j].x += __shfl_xor(aA[j].x, 16, 64);
        aA[j].y += __shfl_xor(aA[j].y, 16, 64);
        aA[j].x += __shfl_xor(aA[j].x, 32, 64);
        aA[j].y += __shfl_xor(aA[j].y, 32, 64);
        aB[j].x += __shfl_xor(aB[j].x, 16, 64);
        aB[j].y += __shfl_xor(aB[j].y, 16, 64);
        aB[j].x += __shfl_xor(aB[j].x, 32, 64);
        aB[j].y += __shfl_xor(aB[j].y, 32, 64);
      }
      if (g < 2) {   // 32 lanes write bf16-packed partials (uint2 each)
        uint2 wA, wB;
        if (g == 0) {
          wA.x = pack2bf(aA[0].x, aA[0].y); wA.y = pack2bf(aA[1].x, aA[1].y);
          wB.x = pack2bf(aB[0].x, aB[0].y); wB.y = pack2bf(aB[1].x, aB[1].y);
        } else {
          wA.x = pack2bf(aA[2].x, aA[2].y); wA.y = pack2bf(aA[3].x, aA[3].y);
          wB.x = pack2bf(aB[2].x, aB[2].y); wB.y = pack2bf(aB[3].x, aB[3].y);
        }
        *(uint2*)&ubuf[r][n][l16 * 4 + g * 2]     = wA;
        *(uint2*)&ubuf[r][n + 1][l16 * 4 + g * 2] = wB;
      }
    }
  };
  if (cnt <= CAP)
    body([&](int e) { return scsr[r][e - beg0]; });
  else
    body([&](int e) { return cs[e]; });
  __syncthreads();

  // Epilogue: 32 threads per node, 4 cols each (uints 2*ln, 2*ln+1).
  int nn = threadIdx.x >> 5;
  int ln = threadIdx.x & 31;
  int d  = d0 + nn;
  float s0 = sinF[d];
  float s1 = sinF[N_NODES + d];
  float s2 = sinF[2 * N_NODES + d];
  float s3 = sinF[3 * N_NODES + d];
  uint2 u0 = *(const uint2*)&ubuf[0][nn][ln * 2];
  uint2 u1 = *(const uint2*)&ubuf[1][nn][ln * 2];
  uint2 u2 = *(const uint2*)&ubuf[2][nn][ln * 2];
  uint2 u3 = *(const uint2*)&ubuf[3][nn][ln * 2];
  float4 bs = *(const float4*)&bsum[ln * 4];
  float v0 = s0 * bf_lo(u0.x) + s1 * bf_lo(u1.x) + s2 * bf_lo(u2.x) +
             s3 * bf_lo(u3.x) + bs.x;
  float v1 = s0 * bf_hi(u0.x) + s1 * bf_hi(u1.x) + s2 * bf_hi(u2.x) +
             s3 * bf_hi(u3.x) + bs.y;
  float v2 = s0 * bf_lo(u0.y) + s1 * bf_lo(u1.y) + s2 * bf_lo(u2.y) +
             s3 * bf_lo(u3.y) + bs.z;
  float v3 = s0 * bf_hi(u0.y) + s1 * bf_hi(u1.y) + s2 * bf_hi(u2.y) +
             s3 * bf_hi(u3.y) + bs.w;
  if (MODE == 1) {
    float ss = v0 * v0 + v1 * v1 + v2 * v2 + v3 * v3;
    ss += __shfl_xor(ss, 1, 32);
    ss += __shfl_xor(ss, 2, 32);
    ss += __shfl_xor(ss, 4, 32);
    ss += __shfl_xor(ss, 8, 32);
    ss += __shfl_xor(ss, 16, 32);
    float sc = 1.0f / fmaxf(sqrtf(ss), 1e-12f);
    v0 *= sc; v1 *= sc; v2 *= sc; v3 *= sc;
    v0 = v0 > 0.f ? v0 : 0.01f * v0;
    v1 = v1 > 0.f ? v1 : 0.01f * v1;
    v2 = v2 > 0.f ? v2 : 0.01f * v2;
    v3 = v3 > 0.f ? v3 : 0.01f * v3;
    uint2 o;
    o.x = pack2bf(v0, v1);
    o.y = pack2bf(v2, v3);
    *(uint2*)((unsigned short*)out + (size_t)d * DIM + ln * 4) = o;
  } else {
    float4 o = make_float4(v0, v1, v2, v3);
    *(float4*)((float*)out + (size_t)d * DIM + ln * 4) = o;
  }
}

// ---------------------------------------------------------------------------
// K6: hg = sum_v wout[v] * h3[v]   (h3 columns are LCOL-permuted; fine)
// ---------------------------------------------------------------------------
__global__ __launch_bounds__(256) void pool_kernel(
    const float* __restrict__ h, const float* __restrict__ wout,
    float* __restrict__ hg) {
  int gw   = blockIdx.x * 4 + (threadIdx.x >> 6);
  int lane = threadIdx.x & 63;
  int nw   = gridDim.x * 4;
  float ax = 0.0f, ay = 0.0f;
  for (int v = gw; v < N_NODES; v += nw) {
    float w = wout[v];
    float2 hv = *(const float2*)(h + (size_t)v * DIM + lane * 2);
    ax = fmaf(w, hv.x, ax);
    ay = fmaf(w, hv.y, ay);
  }
  atomicAdd(&hg[lane * 2],     ax);
  atomicAdd(&hg[lane * 2 + 1], ay);
}

// ---------------------------------------------------------------------------
// K7: head  out = sigmoid( (hg/N) @ Wlin + blin ); hg is LCOL-permuted.
// ---------------------------------------------------------------------------
__global__ void head_kernel(const float* __restrict__ hg,
                            const float* __restrict__ Wlin,
                            const float* __restrict__ blin,
                            float* __restrict__ out) {
  int j = threadIdx.x;
  if (j < N_CLS) {
    float s = blin[j];
    const float invN = 1.0f / (float)N_NODES;
#pragma unroll 16
    for (int k = 0; k < DIM; ++k) {
      int Lk = (k & 7) * 16 + (k >> 3);
      s = fmaf(hg[k] * invN, Wlin[Lk * N_CLS + j], s);
    }
    out[j] = 1.0f / (1.0f + expf(-s));
  }
}

__global__ void fail_kernel(float* out) {
  int i = threadIdx.x;
  if (i < N_CLS) out[i] = 1e30f;
}

// ---------------------------------------------------------------------------
extern "C" void kernel_launch(void* const* d_in, const int* in_sizes, int n_in,
                              void* d_out, int out_size, void* d_ws, size_t ws_size,
                              hipStream_t stream) {
  const float* feat = (const float*)d_in[0];
  const int*   src  = (const int*)  d_in[1];
  const int*   dst  = (const int*)  d_in[2];
  const float* W1   = (const float*)d_in[3];
  const float* b1   = (const float*)d_in[4];
  const float* W2   = (const float*)d_in[5];
  const float* b2   = (const float*)d_in[6];
  const float* W3   = (const float*)d_in[7];
  const float* b3   = (const float*)d_in[8];
  const float* Wlin = (const float*)d_in[9];
  const float* blin = (const float*)d_in[10];
  float* out = (float*)d_out;

  char* base = (char*)d_ws;
  size_t off = 0;
  auto alloc = [&](size_t bytes) -> void* {
    void* q = base + off;
    off = (off + bytes + 255) & ~(size_t)255;
    return q;
  };
  int*   cnt_out  = (int*)  alloc((size_t)N_REL * N_NODES * 4);
  int*   cnt_in   = (int*)  alloc((size_t)N_REL * N_NODES * 4);
  int*   row_ptr  = (int*)  alloc((size_t)N_REL * (N_NODES + 1) * 4);
  float* soutF    = (float*)alloc((size_t)N_REL * N_NODES * 4);
  float* sinF     = (float*)alloc((size_t)N_REL * N_NODES * 4);
  float* wout     = (float*)alloc((size_t)N_NODES * 4);
  float* hg       = (float*)alloc((size_t)DIM * 4);
  int*   partial  = (int*)  alloc((size_t)NPART * 4);
  int*   chunkoff = (int*)  alloc((size_t)NPART * 4);
  int*   cbcur    = (int*)  alloc((size_t)NCB * 4);
  unsigned int*   binned = (unsigned int*)  alloc((size_t)N_REL * N_EDGES * 4);
  unsigned short* csr    = (unsigned short*)alloc((size_t)N_REL * N_EDGES * 2);
  unsigned char*  Yb     = (unsigned char*) alloc((size_t)N_REL * N_PAD * DIM);
  unsigned short* X1     = (unsigned short*)alloc((size_t)N_NODES * DIM * 2);
  unsigned short* X2     = (unsigned short*)alloc((size_t)N_NODES * DIM * 2);
  float* H3       = (float*)alloc((size_t)N_NODES * DIM * 4);
  unsigned short* Wt1 = (unsigned short*)alloc((size_t)N_REL * DIM * DIM * 2);
  unsigned short* Wt2 = (unsigned short*)alloc((size_t)N_REL * DIM * DIM * 2);
  unsigned short* Wt3 = (unsigned short*)alloc((size_t)N_REL * DIM * DIM * 2);
  float* bs1 = (float*)alloc(DIM * 4);
  float* bs2 = (float*)alloc(DIM * 4);
  float* bs3 = (float*)alloc(DIM * 4);

  if (off > ws_size) {  // unambiguous sentinel instead of OOB writes
    fail_kernel<<<1, 64, 0, stream>>>(out);
    return;
  }

  hipMemsetAsync(cnt_out, 0, (size_t)2 * N_REL * N_NODES * 4, stream);
  hipMemsetAsync(hg, 0, DIM * 4, stream);

  // CSR build: degree (LDS hist) -> row_ptr(+bin cursors+scales) -> bin -> sort
  degree_hist  <<<2 * N_REL * NRANGE * DNT, 256, 0, stream>>>(src, dst, cnt_out, cnt_in);
  scan_partial <<<NPART, 256, 0, stream>>>(cnt_in, partial);
  scan_offsets <<<1, 1024, 0, stream>>>(partial, chunkoff, row_ptr);
  scan_expand  <<<NPART, 256, 0, stream>>>(cnt_in, chunkoff, row_ptr, cbcur,
                                           cnt_out, soutF, sinF, wout);
  pass1_bin    <<<N_REL * TPR, 256, 0, stream>>>(src, dst, cbcur, binned);
  pass2_sort   <<<NCB, 256, 0, stream>>>(binned, row_ptr, csr);

  // Weight prep (single launch, 3 sets) + one-time sentinel-row zeroing
  prep_w3<<<3 * 256, 256, 0, stream>>>(W1, b1, W2, b2, W3, b3,
                                       Wt1, bs1, Wt2, bs2, Wt3, bs3);
  zero_pad<<<6, 256, 0, stream>>>(Yb);

  int gemm_blocks = N_PAD / 64;                  // 782 (last block: A rows 0)
  int gath_blocks = (N_NODES + NPB - 1) / NPB;   // 6250, exact

  // Layer 1: transform-then-aggregate (GEMM reads f32 feat directly)
  gemm_y<1>  <<<gemm_blocks, 256, 0, stream>>>(feat, Wt1, soutF, Yb);
  gather_y<1><<<gath_blocks, 256, 0, stream>>>(Yb, csr, row_ptr, sinF, bs1, X1);
  // Layer 2
  gemm_y<0>  <<<gemm_blocks, 256, 0, stream>>>(X1, Wt2, soutF, Yb);
  gather_y<1><<<gath_blocks, 256, 0, stream>>>(Yb, csr, row_ptr, sinF, bs2, X2);
  // Layer 3 (no norm/act, f32 out)
  gemm_y<0>  <<<gemm_blocks, 256, 0, stream>>>(X2, Wt3, soutF, Yb);
  gather_y<0><<<gath_blocks, 256, 0, stream>>>(Yb, csr, row_ptr, sinF, bs3, H3);

  // Pool + head
  pool_kernel<<<256, 256, 0, stream>>>(H3, wout, hg);
  head_kernel<<<1, 64, 0, stream>>>(hg, Wlin, blin, out);
}

// Round 12
// 484.270 us; speedup vs baseline: 1.3434x; 1.0053x over previous
//
#include <hip/hip_runtime.h>
#include <hip/hip_bf16.h>

// Problem constants (fixed by the reference).
constexpr int N_NODES = 50000;
constexpr int N_REL   = 4;
constexpr int N_EDGES = 800000;
constexpr int DIM     = 128;     // IN_DIM == HID == 128
constexpr int N_CLS   = 16;

// Coarse bins: 256 dst nodes per bin (dst>>8).
constexpr int NCBR  = (N_NODES + 255) / 256;   // 196
constexpr int NCB   = N_REL * NCBR;            // 784
constexpr int TILE  = 8000;                    // edges per pass0/pass1 block
constexpr int TPR   = N_EDGES / TILE;          // 100 (exact)
constexpr int MAXB  = 6144;                    // bin capacity for LDS sort path

// Out-degree histogram decomposition (round-2 proven; fewer-pass variants
// regressed — parallelism + coalesced writes win): node ranges of 12544
// (49 KB LDS), edge tiles of 80000. Src side only (in-degree now comes
// from pass2's per-bin histogram).
constexpr int RNG    = 12544;
constexpr int NRANGE = 4;                      // 4*12544 = 50176 >= 50000
constexpr int DTILE  = 80000;
constexpr int DNT    = N_EDGES / DTILE;        // 10 (exact)

// Gather batching: 8 dst nodes per block (6250 blocks, exact: 6250*8=50000).
constexpr int NPB = 8;
// Per-relation LDS capacity for the staged csr segment (avg 128, sigma~11;
// 512 is a >30-sigma bound; global-read fallback otherwise).
constexpr int CAP = 512;

// Y table padded rows: row N_NODES per relation is a zero sentinel row
// (written once by zero_pad, never touched by the gemm) — gather tail
// loads hit it and contribute 0.
constexpr int N_PAD = 50048;

// fp8 range scale: Y = YS * sout * (x@W); inverse folded into sinF.
constexpr float YSCALE = 32.0f;

typedef __attribute__((ext_vector_type(8))) short short8;
typedef __attribute__((ext_vector_type(4))) float float4v;
typedef __attribute__((ext_vector_type(2))) float floatx2;

// ---- bf16 helpers (manual, round-to-nearest-even) -------------------------
__device__ __forceinline__ unsigned int f2bf_bits(float f) {
  unsigned int u = __float_as_uint(f);
  return (u + 0x7fffu + ((u >> 16) & 1u)) >> 16;
}
__device__ __forceinline__ unsigned int pack2bf(float a, float b) {
  return f2bf_bits(a) | (f2bf_bits(b) << 16);
}
__device__ __forceinline__ float bf_lo(unsigned int u) { return __uint_as_float(u << 16); }
__device__ __forceinline__ float bf_hi(unsigned int u) { return __uint_as_float(u & 0xffff0000u); }

// Column permutation: stored position p <-> logical column (p&7)*16 + (p>>3).
// (Comes from the GEMM epilogue's lane-packed fp8 stores; carried
// consistently through Y -> gather -> X -> next-layer W rows -> head.)
__device__ __forceinline__ int LCOL(int p) { return (p & 7) * 16 + (p >> 3); }

// ---------------------------------------------------------------------------
// K0: OUT-degree histogram (src side only) via block-local LDS ranges +
// coalesced atomic flush. (round-2 structure — best measured variant)
// ---------------------------------------------------------------------------
__global__ __launch_bounds__(256) void degree_hist_src(
    const int* __restrict__ src, int* __restrict__ cnt_out) {
  int b = blockIdx.x;
  int t     = b % DNT;    b /= DNT;
  int range = b % NRANGE; b /= NRANGE;
  int r     = b;
  const int* arr = src + (size_t)r * N_EDGES + (size_t)t * DTILE;
  int* cnt = cnt_out + r * N_NODES;
  int tid = threadIdx.x;
  __shared__ int h[RNG];
  for (int i = tid; i < RNG; i += 256) h[i] = 0;
  __syncthreads();
  int lo = range * RNG;
  int hi = lo + RNG;
  const int4* a4 = (const int4*)arr;
  for (int i = tid; i < DTILE / 4; i += 256) {
    int4 v = a4[i];
    if (v.x >= lo && v.x < hi) atomicAdd(&h[v.x - lo], 1);
    if (v.y >= lo && v.y < hi) atomicAdd(&h[v.y - lo], 1);
    if (v.z >= lo && v.z < hi) atomicAdd(&h[v.z - lo], 1);
    if (v.w >= lo && v.w < hi) atomicAdd(&h[v.w - lo], 1);
  }
  __syncthreads();
  for (int i = tid; i < RNG; i += 256) {
    int n = lo + i;
    int c = h[i];
    if (n < N_NODES && c) atomicAdd(&cnt[n], c);
  }
}

// ---------------------------------------------------------------------------
// Pass 0: coarse bin counts (196 bins/relation) — one cheap read of dst.
// ---------------------------------------------------------------------------
__global__ __launch_bounds__(256) void pass0_coarse(
    const int* __restrict__ dst, int* __restrict__ binCnt) {
  int b = blockIdx.x;
  int r = b / TPR, t = b % TPR;
  const int* dp = dst + (size_t)r * N_EDGES + t * TILE;
  int tid = threadIdx.x;
  __shared__ int hist[NCBR];
  for (int i = tid; i < NCBR; i += 256) hist[i] = 0;
  __syncthreads();
  for (int i = tid; i < TILE; i += 256) atomicAdd(&hist[dp[i] >> 8], 1);
  __syncthreads();
  for (int i = tid; i < NCBR; i += 256) {
    int c = hist[i];
    if (c) atomicAdd(&binCnt[r * NCBR + i], c);
  }
}

// ---------------------------------------------------------------------------
// scan_bins: 1 block prefixes the 784 bin counts -> global bin starts
// (bstart, NCB+1 entries) + relation-relative scatter cursors (cbcur);
// also writes the constant row_ptr totals.
// ---------------------------------------------------------------------------
__global__ __launch_bounds__(1024) void scan_bins(
    const int* __restrict__ binCnt, int* __restrict__ bstart,
    int* __restrict__ cbcur, int* __restrict__ row_ptr) {
  __shared__ int lds[1024];
  int tid = threadIdx.x;
  int v = (tid < NCB) ? binCnt[tid] : 0;
  lds[tid] = v;
  __syncthreads();
  for (int off = 1; off < 1024; off <<= 1) {
    int t = (tid >= off) ? lds[tid - off] : 0;
    __syncthreads();
    lds[tid] += t;
    __syncthreads();
  }
  int excl = lds[tid] - v;
  if (tid < NCB) {
    bstart[tid] = excl;
    int r = tid / NCBR;
    cbcur[tid] = excl - r * N_EDGES;   // relation-relative cursor
  }
  if (tid == NCB - 1) bstart[NCB] = excl + v;
  if (tid < N_REL) row_ptr[tid * (N_NODES + 1) + N_NODES] = N_EDGES;
}

// ---------------------------------------------------------------------------
// Pass 1: per-block LDS binning into 196 coarse bins; one global atomic per
// (block,bin) reserves a contiguous chunk. Payload: src<<8 | dst&255.
// (LDS-staged, coalesced chunk writes — direct global scatter costs ~32x
// write amplification across non-coherent XCD L2s, measured round 9.)
// ---------------------------------------------------------------------------
__global__ __launch_bounds__(256) void pass1_bin(
    const int* __restrict__ src, const int* __restrict__ dst,
    int* __restrict__ cbcur, unsigned int* __restrict__ binned) {
  int b = blockIdx.x;
  int r = b / TPR, t = b % TPR;
  const int* sp = src + (size_t)r * N_EDGES + t * TILE;
  const int* dp = dst + (size_t)r * N_EDGES + t * TILE;
  unsigned int* outp = binned + (size_t)r * N_EDGES;
  int tid = threadIdx.x;
  __shared__ int hist[NCBR];
  __shared__ int scanb[256];
  __shared__ int gbase[NCBR];
  __shared__ int lcur[NCBR];
  for (int i = tid; i < NCBR; i += 256) hist[i] = 0;
  __syncthreads();
  for (int i = tid; i < TILE; i += 256) atomicAdd(&hist[dp[i] >> 8], 1);
  __syncthreads();
  int v = (tid < NCBR) ? hist[tid] : 0;
  scanb[tid] = v;
  __syncthreads();
  for (int off = 1; off < 256; off <<= 1) {
    int tv = (tid >= off) ? scanb[tid - off] : 0;
    __syncthreads();
    scanb[tid] += tv;
    __syncthreads();
  }
  if (tid < NCBR) {
    int excl = scanb[tid] - v;
    gbase[tid] = atomicAdd(&cbcur[r * NCBR + tid], v) - excl;
    lcur[tid] = excl;
  }
  __syncthreads();
  for (int i = tid; i < TILE; i += 256) {
    int d = dp[i];
    int s = sp[i];
    int cb = d >> 8;
    int lp = atomicAdd(&lcur[cb], 1);
    outp[gbase[cb] + lp] = ((unsigned)s << 8) | (unsigned)(d & 255);
  }
}

// ---------------------------------------------------------------------------
// Pass 2: one block per coarse bin; LDS counting sort by dst&255.
// The per-key histogram IS the in-degree of the bin's 256 nodes, so this
// kernel also emits row_ptr (binStart + within-bin exclusive scan), sinF,
// soutF (from cnt_out) and wout — replacing the old cnt_in pipeline.
// ---------------------------------------------------------------------------
__global__ __launch_bounds__(256) void pass2_sort(
    const unsigned int* __restrict__ binned, const int* __restrict__ bstart,
    const int* __restrict__ cnt_out, int* __restrict__ row_ptr,
    float* __restrict__ soutF, float* __restrict__ sinF,
    float* __restrict__ wout, unsigned short* __restrict__ csr) {
  int b = blockIdx.x;
  int r = b / NCBR, c = b % NCBR;
  int gstart = bstart[b];
  int count  = bstart[b + 1] - gstart;
  int start  = gstart - r * N_EDGES;      // relation-relative
  const unsigned int* bp = binned + (size_t)r * N_EDGES + start;
  unsigned short* outg = csr + (size_t)r * N_EDGES + start;
  int tid = threadIdx.x;
  __shared__ int hist[256];
  __shared__ int scanb[256];
  __shared__ unsigned short outb[MAXB];
  hist[tid] = 0;
  __syncthreads();
  for (int i = tid; i < count; i += 256) atomicAdd(&hist[bp[i] & 255u], 1);
  __syncthreads();
  int v = hist[tid];
  scanb[tid] = v;
  __syncthreads();
  for (int off = 1; off < 256; off <<= 1) {
    int tv = (tid >= off) ? scanb[tid - off] : 0;
    __syncthreads();
    scanb[tid] += tv;
    __syncthreads();
  }
  int excl = scanb[tid] - v;
  int node = c * 256 + tid;
  if (node < N_NODES) {
    row_ptr[r * (N_NODES + 1) + node] = start + excl;
    sinF[r * N_NODES + node] = (1.0f / YSCALE) / sqrtf((float)max(v, 1));
    int co = cnt_out[r * N_NODES + node];
    soutF[r * N_NODES + node] = YSCALE / sqrtf((float)max(co, 1));
    if (r == 0) {
      wout[node] = (float)(co + cnt_out[N_NODES + node] +
                           cnt_out[2 * N_NODES + node] +
                           cnt_out[3 * N_NODES + node]);
    }
  }
  hist[tid] = excl;                       // exclusive start -> running cursor
  __syncthreads();
  if (count <= MAXB) {
    for (int i = tid; i < count; i += 256) {
      unsigned int p = bp[i];
      int pos = atomicAdd(&hist[p & 255u], 1);
      outb[pos] = (unsigned short)(p >> 8);
    }
    __syncthreads();
    for (int i = tid; i < count; i += 256) outg[i] = outb[i];
  } else {
    for (int i = tid; i < count; i += 256) {
      unsigned int p = bp[i];
      int pos = atomicAdd(&hist[p & 255u], 1);
      outg[pos] = (unsigned short)(p >> 8);
    }
  }
}

// ---------------------------------------------------------------------------
// Weight prep (all 3 layers in one launch):
// W[4][128][128] f32 -> Wt[512 cols][128 k] bf16; bsum permuted.
// Layer 1 uses logical k order; layers 2,3 use LCOL-permuted k (their X
// input is the permuted gather output).
// ---------------------------------------------------------------------------
__global__ __launch_bounds__(256) void prep_w3(
    const float* __restrict__ W1, const float* __restrict__ b1,
    const float* __restrict__ W2, const float* __restrict__ b2,
    const float* __restrict__ W3, const float* __restrict__ b3,
    unsigned short* __restrict__ Wt1, float* __restrict__ bs1,
    unsigned short* __restrict__ Wt2, float* __restrict__ bs2,
    unsigned short* __restrict__ Wt3, float* __restrict__ bs3) {
  int set = blockIdx.x >> 8;                // 256 blocks per weight set
  int i   = (blockIdx.x & 255) * 256 + threadIdx.x;
  const float* W = (set == 0) ? W1 : (set == 1) ? W2 : W3;
  const float* b = (set == 0) ? b1 : (set == 1) ? b2 : b3;
  unsigned short* Wt = (set == 0) ? Wt1 : (set == 1) ? Wt2 : Wt3;
  float* bsum = (set == 0) ? bs1 : (set == 1) ? bs2 : bs3;
  int permk = (set != 0);
  if (i < N_REL * DIM * DIM) {
    int col = i >> 7, p = i & 127;
    int k = permk ? LCOL(p) : p;
    int rrel = col >> 7, n = col & 127;
    Wt[i] = (unsigned short)f2bf_bits(W[rrel * DIM * DIM + k * DIM + n]);
  }
  if (i < DIM) {
    int Lp = LCOL(i);
    bsum[i] = b[Lp] + b[DIM + Lp] + b[2 * DIM + Lp] + b[3 * DIM + Lp];
  }
}

// ---------------------------------------------------------------------------
// zero_pad: write the 48 pad rows (incl. the sentinel row N_NODES) of each
// relation's Y table as zeros, ONCE. The gemm never touches these rows, so
// they remain zero across all 3 layers.
// ---------------------------------------------------------------------------
__global__ __launch_bounds__(256) void zero_pad(unsigned char* __restrict__ Yb) {
  constexpr int PER = (N_PAD - N_NODES) * DIM / 16;   // 384 uint4 per relation
  int tid = blockIdx.x * 256 + threadIdx.x;
  int r = tid / PER, k = tid % PER;
  if (r < N_REL) {
    uint4* p = (uint4*)(Yb + (size_t)r * N_PAD * DIM + (size_t)N_NODES * DIM);
    p[k] = make_uint4(0u, 0u, 0u, 0u);
  }
}

// ---------------------------------------------------------------------------
// K5: MFMA GEMM  Y[r][row][p] = fp8( soutF[r][row] * (X[row,:] @ W_r)[LCOL(p)] )
// AF32=1: A is the raw f32 feat (layer 1) — packed to bf16 in the loader.
// AF32=0: A is bf16 [N][128].
// Block = 64 rows x 512 cols; wave w owns relation/quadrant w (128 cols).
// Epilogue: only rows < N_NODES are written (pad/sentinel rows are zeroed
// once by zero_pad, never touched here).
// ---------------------------------------------------------------------------
template <int AF32>
__global__ __launch_bounds__(256) void gemm_y(
    const void* __restrict__ Xv, const unsigned short* __restrict__ Wt,
    const float* __restrict__ soutF, unsigned char* __restrict__ Yb) {
  int tid = threadIdx.x;
  int w   = tid >> 6;           // relation / column quadrant
  int l   = tid & 63;
  int l15 = l & 15, lq = l >> 4;
  int rowbase = blockIdx.x * 64;

  const unsigned short* X = (const unsigned short*)Xv;
  const float*          Xf = (const float*)Xv;

  float4v acc[4][8] = {};
  const unsigned short* Wq = Wt + (size_t)(w * DIM) * DIM;

#pragma unroll
  for (int ks = 0; ks < 4; ++ks) {
    int k0 = ks * 32 + lq * 8;
    short8 bfr[8];
#pragma unroll
    for (int c = 0; c < 8; ++c)
      bfr[c] = *(const short8*)(Wq + (size_t)(c * 16 + l15) * DIM + k0);
#pragma unroll
    for (int i = 0; i < 4; ++i) {
      int rr = rowbase + i * 16 + l15;
      short8 afr;
      if (rr < N_NODES) {
        if (AF32) {
          const float* xp = Xf + (size_t)rr * DIM + k0;
          float4 f0 = *(const float4*)xp;
          float4 f1 = *(const float4*)(xp + 4);
          afr[0] = (short)f2bf_bits(f0.x);
          afr[1] = (short)f2bf_bits(f0.y);
          afr[2] = (short)f2bf_bits(f0.z);
          afr[3] = (short)f2bf_bits(f0.w);
          afr[4] = (short)f2bf_bits(f1.x);
          afr[5] = (short)f2bf_bits(f1.y);
          afr[6] = (short)f2bf_bits(f1.z);
          afr[7] = (short)f2bf_bits(f1.w);
        } else {
          afr = *(const short8*)(X + (size_t)rr * DIM + k0);
        }
      } else {
        afr = (short8)(short)0;
      }
#pragma unroll
      for (int c = 0; c < 8; ++c)
        acc[i][c] = __builtin_amdgcn_mfma_f32_16x16x32_bf16(afr, bfr[c],
                                                            acc[i][c], 0, 0, 0);
    }
  }

  const float* so = soutF + (size_t)w * N_NODES;
  unsigned char* Yq = Yb + (size_t)w * N_PAD * DIM;
#pragma unroll
  for (int i = 0; i < 4; ++i) {
#pragma unroll
    for (int rr = 0; rr < 4; ++rr) {
      int grow = rowbase + i * 16 + lq * 4 + rr;
      if (grow < N_NODES) {
        float sc = so[grow];
        float v0 = acc[i][0][rr] * sc, v1 = acc[i][1][rr] * sc;
        float v2 = acc[i][2][rr] * sc, v3 = acc[i][3][rr] * sc;
        float v4 = acc[i][4][rr] * sc, v5 = acc[i][5][rr] * sc;
        float v6 = acc[i][6][rr] * sc, v7 = acc[i][7][rr] * sc;
        int t0 = __builtin_amdgcn_cvt_pk_fp8_f32(v0, v1, 0, false);
        t0 = __builtin_amdgcn_cvt_pk_fp8_f32(v2, v3, t0, true);
        int t1 = __builtin_amdgcn_cvt_pk_fp8_f32(v4, v5, 0, false);
        t1 = __builtin_amdgcn_cvt_pk_fp8_f32(v6, v7, t1, true);
        uint2 o;
        o.x = (unsigned)t0;
        o.y = (unsigned)t1;
        *(uint2*)(Yq + (size_t)grow * DIM + l15 * 8) = o;
      }
    }
  }
}

// ---------------------------------------------------------------------------
// K4: fused gather, 8 dst nodes per block (round-7 proven: pair-interleave,
// sentinel-padded tails, csr LDS staging, bf16-packed reduce buffer,
// ~12.5 KB LDS -> 8 blocks/CU).
// Epilogue: 32 threads per node: sin, bias, (l2norm + leaky for MODE 1):
//   MODE 1: bf16 X_{l+1}  (next GEMM's A operand)
//   MODE 0: f32  H3       (pool input)
// ---------------------------------------------------------------------------
template <int MODE>
__global__ __launch_bounds__(256) void gather_y(
    const unsigned char* __restrict__ Yb, const unsigned short* __restrict__ csr,
    const int* __restrict__ row_ptr, const float* __restrict__ sinF,
    const float* __restrict__ bsum, void* __restrict__ out) {
  int d0   = blockIdx.x * NPB;
  int r    = threadIdx.x >> 6;
  int lane = threadIdx.x & 63;
  int g    = lane >> 4;   // edge group 0..3
  int l16  = lane & 15;   // covers stored bytes l16*8 .. l16*8+7
  const unsigned short* cs = csr + (size_t)r * N_EDGES;
  const unsigned char*  Yq = Yb + (size_t)r * N_PAD * DIM;

  // lanes 0..8 hold row_ptr[d0..d0+8] (coalesced; d0+NPB <= N_NODES exact)
  int rp = row_ptr[r * (N_NODES + 1) + d0 + min(lane, NPB)];
  int beg0 = __shfl(rp, 0, 64);
  int cnt  = __shfl(rp, NPB, 64) - beg0;

  __shared__ unsigned short scsr[N_REL][CAP];
  __shared__ __align__(16) unsigned int ubuf[N_REL][NPB][66];  // bf16-packed

  int ccap = min(cnt, CAP);
  for (int i = lane; i < ccap; i += 64) scsr[r][i] = cs[beg0 + i];
  // wave-local LDS use only (wave == relation): compiler-inserted lgkmcnt
  // orders the reads below; no block barrier needed before the n-loop.

  auto body = [&](auto CS) {
#pragma unroll 1
    for (int n = 0; n < NPB; n += 2) {
      int bA = __shfl(rp, n, 64),  eA = __shfl(rp, n + 1, 64);
      int bB = eA,                 eB = __shfl(rp, n + 2, 64);
      floatx2 aA[4], aB[4];
#pragma unroll
      for (int j = 0; j < 4; ++j) {
        aA[j] = (floatx2){0.f, 0.f};
        aB[j] = (floatx2){0.f, 0.f};
      }
      int pA = bA, pB = bB;
      while (pA < eA || pB < eB) {
        bool doA = pA < eA, doB = pB < eB;
        uint2 xA[4], xB[4];
        if (doA) {
#pragma unroll
          for (int u = 0; u < 4; ++u) {
            int e = pA + u * 4 + g;
            int se = (e < eA) ? (int)CS(e) : N_NODES;   // zero sentinel row
            xA[u] = *(const uint2*)(Yq + (size_t)se * DIM + l16 * 8);
          }
        }
        if (doB) {
#pragma unroll
          for (int u = 0; u < 4; ++u) {
            int e = pB + u * 4 + g;
            int se = (e < eB) ? (int)CS(e) : N_NODES;
            xB[u] = *(const uint2*)(Yq + (size_t)se * DIM + l16 * 8);
          }
        }
        if (doA) {
#pragma unroll
          for (int u = 0; u < 4; ++u) {
            aA[0] += __builtin_amdgcn_cvt_pk_f32_fp8((int)xA[u].x, false);
            aA[1] += __builtin_amdgcn_cvt_pk_f32_fp8((int)xA[u].x, true);
            aA[2] += __builtin_amdgcn_cvt_pk_f32_fp8((int)xA[u].y, false);
            aA[3] += __builtin_amdgcn_cvt_pk_f32_fp8((int)xA[u].y, true);
          }
          pA += 16;
        }
        if (doB) {
#pragma unroll
          for (int u = 0; u < 4; ++u) {
            aB[0] += __builtin_amdgcn_cvt_pk_f32_fp8((int)xB[u].x, false);
            aB[1] += __builtin_amdgcn_cvt_pk_f32_fp8((int)xB[u].x, true);
            aB[2] += __builtin_amdgcn_cvt_pk_f32_fp8((int)xB[u].y, false);
            aB[3] += __builtin_amdgcn_cvt_pk_f32_fp8((int)xB[u].y, true);
          }
          pB += 16;
        }
      }
      // reduce the 4 edge-groups within the wave (both nodes)
#pragma unroll
      for (int j = 0; j < 4; ++j) {
        aA[j].x += __shfl_xor(aA[j].x, 16, 64);
        aA[j].y += __shfl_xor(aA[j].y, 16, 64);
        aA[j].x += __shfl_xor(aA[j].x, 32, 64);
        aA[j].y += __shfl_xor(aA[j].y, 32, 64);
        aB[j].x += __shfl_xor(aB[j].x, 16, 64);
        aB[j].y += __shfl_xor(aB[j].y, 16, 64);
        aB[j].x += __shfl_xor(aB[j].x, 32, 64);
        aB[j].y += __shfl_xor(aB[j].y, 32, 64);
      }
      if (g < 2) {   // 32 lanes write bf16-packed partials (uint2 each)
        uint2 wA, wB;
        if (g == 0) {
          wA.x = pack2bf(aA[0].x, aA[0].y); wA.y = pack2bf(aA[1].x, aA[1].y);
          wB.x = pack2bf(aB[0].x, aB[0].y); wB.y = pack2bf(aB[1].x, aB[1].y);
        } else {
          wA.x = pack2bf(aA[2].x, aA[2].y); wA.y = pack2bf(aA[3].x, aA[3].y);
          wB.x = pack2bf(aB[2].x, aB[2].y); wB.y = pack2bf(aB[3].x, aB[3].y);
        }
        *(uint2*)&ubuf[r][n][l16 * 4 + g * 2]     = wA;
        *(uint2*)&ubuf[r][n + 1][l16 * 4 + g * 2] = wB;
      }
    }
  };
  if (cnt <= CAP)
    body([&](int e) { return scsr[r][e - beg0]; });
  else
    body([&](int e) { return cs[e]; });
  __syncthreads();

  // Epilogue: 32 threads per node, 4 cols each (uints 2*ln, 2*ln+1).
  int nn = threadIdx.x >> 5;
  int ln = threadIdx.x & 31;
  int d  = d0 + nn;
  float s0 = sinF[d];
  float s1 = sinF[N_NODES + d];
  float s2 = sinF[2 * N_NODES + d];
  float s3 = sinF[3 * N_NODES + d];
  uint2 u0 = *(const uint2*)&ubuf[0][nn][ln * 2];
  uint2 u1 = *(const uint2*)&ubuf[1][nn][ln * 2];
  uint2 u2 = *(const uint2*)&ubuf[2][nn][ln * 2];
  uint2 u3 = *(const uint2*)&ubuf[3][nn][ln * 2];
  float4 bs = *(const float4*)&bsum[ln * 4];
  float v0 = s0 * bf_lo(u0.x) + s1 * bf_lo(u1.x) + s2 * bf_lo(u2.x) +
             s3 * bf_lo(u3.x) + bs.x;
  float v1 = s0 * bf_hi(u0.x) + s1 * bf_hi(u1.x) + s2 * bf_hi(u2.x) +
             s3 * bf_hi(u3.x) + bs.y;
  float v2 = s0 * bf_lo(u0.y) + s1 * bf_lo(u1.y) + s2 * bf_lo(u2.y) +
             s3 * bf_lo(u3.y) + bs.z;
  float v3 = s0 * bf_hi(u0.y) + s1 * bf_hi(u1.y) + s2 * bf_hi(u2.y) +
             s3 * bf_hi(u3.y) + bs.w;
  if (MODE == 1) {
    float ss = v0 * v0 + v1 * v1 + v2 * v2 + v3 * v3;
    ss += __shfl_xor(ss, 1, 32);
    ss += __shfl_xor(ss, 2, 32);
    ss += __shfl_xor(ss, 4, 32);
    ss += __shfl_xor(ss, 8, 32);
    ss += __shfl_xor(ss, 16, 32);
    float sc = 1.0f / fmaxf(sqrtf(ss), 1e-12f);
    v0 *= sc; v1 *= sc; v2 *= sc; v3 *= sc;
    v0 = v0 > 0.f ? v0 : 0.01f * v0;
    v1 = v1 > 0.f ? v1 : 0.01f * v1;
    v2 = v2 > 0.f ? v2 : 0.01f * v2;
    v3 = v3 > 0.f ? v3 : 0.01f * v3;
    uint2 o;
    o.x = pack2bf(v0, v1);
    o.y = pack2bf(v2, v3);
    *(uint2*)((unsigned short*)out + (size_t)d * DIM + ln * 4) = o;
  } else {
    float4 o = make_float4(v0, v1, v2, v3);
    *(float4*)((float*)out + (size_t)d * DIM + ln * 4) = o;
  }
}

// ---------------------------------------------------------------------------
// K6: hg = sum_v wout[v] * h3[v]   (h3 columns are LCOL-permuted; fine)
// ---------------------------------------------------------------------------
__global__ __launch_bounds__(256) void pool_kernel(
    const float* __restrict__ h, const float* __restrict__ wout,
    float* __restrict__ hg) {
  int gw   = blockIdx.x * 4 + (threadIdx.x >> 6);
  int lane = threadIdx.x & 63;
  int nw   = gridDim.x * 4;
  float ax = 0.0f, ay = 0.0f;
  for (int v = gw; v < N_NODES; v += nw) {
    float w = wout[v];
    float2 hv = *(const float2*)(h + (size_t)v * DIM + lane * 2);
    ax = fmaf(w, hv.x, ax);
    ay = fmaf(w, hv.y, ay);
  }
  atomicAdd(&hg[lane * 2],     ax);
  atomicAdd(&hg[lane * 2 + 1], ay);
}

// ---------------------------------------------------------------------------
// K7: head  out = sigmoid( (hg/N) @ Wlin + blin ); hg is LCOL-permuted.
// ---------------------------------------------------------------------------
__global__ void head_kernel(const float* __restrict__ hg,
                            const float* __restrict__ Wlin,
                            const float* __restrict__ blin,
                            float* __restrict__ out) {
  int j = threadIdx.x;
  if (j < N_CLS) {
    float s = blin[j];
    const float invN = 1.0f / (float)N_NODES;
#pragma unroll 16
    for (int k = 0; k < DIM; ++k) {
      int Lk = (k & 7) * 16 + (k >> 3);
      s = fmaf(hg[k] * invN, Wlin[Lk * N_CLS + j], s);
    }
    out[j] = 1.0f / (1.0f + expf(-s));
  }
}

__global__ void fail_kernel(float* out) {
  int i = threadIdx.x;
  if (i < N_CLS) out[i] = 1e30f;
}

// ---------------------------------------------------------------------------
extern "C" void kernel_launch(void* const* d_in, const int* in_sizes, int n_in,
                              void* d_out, int out_size, void* d_ws, size_t ws_size,
                              hipStream_t stream) {
  const float* feat = (const float*)d_in[0];
  const int*   src  = (const int*)  d_in[1];
  const int*   dst  = (const int*)  d_in[2];
  const float* W1   = (const float*)d_in[3];
  const float* b1   = (const float*)d_in[4];
  const float* W2   = (const float*)d_in[5];
  const float* b2   = (const float*)d_in[6];
  const float* W3   = (const float*)d_in[7];
  const float* b3   = (const float*)d_in[8];
  const float* Wlin = (const float*)d_in[9];
  const float* blin = (const float*)d_in[10];
  float* out = (float*)d_out;

  char* base = (char*)d_ws;
  size_t off = 0;
  auto alloc = [&](size_t bytes) -> void* {
    void* q = base + off;
    off = (off + bytes + 255) & ~(size_t)255;
    return q;
  };
  int*   cnt_out  = (int*)  alloc((size_t)N_REL * N_NODES * 4);
  int*   row_ptr  = (int*)  alloc((size_t)N_REL * (N_NODES + 1) * 4);
  float* soutF    = (float*)alloc((size_t)N_REL * N_NODES * 4);
  float* sinF     = (float*)alloc((size_t)N_REL * N_NODES * 4);
  float* wout     = (float*)alloc((size_t)N_NODES * 4);
  float* hg       = (float*)alloc((size_t)DIM * 4);
  int*   binCnt   = (int*)  alloc((size_t)NCB * 4);
  int*   bstart   = (int*)  alloc((size_t)(NCB + 1) * 4);
  int*   cbcur    = (int*)  alloc((size_t)NCB * 4);
  unsigned int*   binned = (unsigned int*)  alloc((size_t)N_REL * N_EDGES * 4);
  unsigned short* csr    = (unsigned short*)alloc((size_t)N_REL * N_EDGES * 2);
  unsigned char*  Yb     = (unsigned char*) alloc((size_t)N_REL * N_PAD * DIM);
  unsigned short* X1     = (unsigned short*)alloc((size_t)N_NODES * DIM * 2);
  unsigned short* X2     = (unsigned short*)alloc((size_t)N_NODES * DIM * 2);
  float* H3       = (float*)alloc((size_t)N_NODES * DIM * 4);
  unsigned short* Wt1 = (unsigned short*)alloc((size_t)N_REL * DIM * DIM * 2);
  unsigned short* Wt2 = (unsigned short*)alloc((size_t)N_REL * DIM * DIM * 2);
  unsigned short* Wt3 = (unsigned short*)alloc((size_t)N_REL * DIM * DIM * 2);
  float* bs1 = (float*)alloc(DIM * 4);
  float* bs2 = (float*)alloc(DIM * 4);
  float* bs3 = (float*)alloc(DIM * 4);

  if (off > ws_size) {  // unambiguous sentinel instead of OOB writes
    fail_kernel<<<1, 64, 0, stream>>>(out);
    return;
  }

  hipMemsetAsync(cnt_out, 0, (size_t)N_REL * N_NODES * 4, stream);
  hipMemsetAsync(binCnt, 0, (size_t)NCB * 4, stream);
  hipMemsetAsync(hg, 0, DIM * 4, stream);

  // CSR build: out-degree hist (src) -> coarse bin count (dst) -> bin-scan
  // -> pass1 bin -> pass2 sort (also emits row_ptr/sinF/soutF/wout).
  degree_hist_src<<<N_REL * NRANGE * DNT, 256, 0, stream>>>(src, cnt_out);
  pass0_coarse   <<<N_REL * TPR, 256, 0, stream>>>(dst, binCnt);
  scan_bins      <<<1, 1024, 0, stream>>>(binCnt, bstart, cbcur, row_ptr);
  pass1_bin      <<<N_REL * TPR, 256, 0, stream>>>(src, dst, cbcur, binned);
  pass2_sort     <<<NCB, 256, 0, stream>>>(binned, bstart, cnt_out, row_ptr,
                                           soutF, sinF, wout, csr);

  // Weight prep (single launch, 3 sets) + one-time sentinel-row zeroing
  prep_w3<<<3 * 256, 256, 0, stream>>>(W1, b1, W2, b2, W3, b3,
                                       Wt1, bs1, Wt2, bs2, Wt3, bs3);
  zero_pad<<<6, 256, 0, stream>>>(Yb);

  int gemm_blocks = N_PAD / 64;                  // 782 (last block: A rows 0)
  int gath_blocks = (N_NODES + NPB - 1) / NPB;   // 6250, exact

  // Layer 1: transform-then-aggregate (GEMM reads f32 feat directly)
  gemm_y<1>  <<<gemm_blocks, 256, 0, stream>>>(feat, Wt1, soutF, Yb);
  gather_y<1><<<gath_blocks, 256, 0, stream>>>(Yb, csr, row_ptr, sinF, bs1, X1);
  // Layer 2
  gemm_y<0>  <<<gemm_blocks, 256, 0, stream>>>(X1, Wt2, soutF, Yb);
  gather_y<1><<<gath_blocks, 256, 0, stream>>>(Yb, csr, row_ptr, sinF, bs2, X2);
  // Layer 3 (no norm/act, f32 out)
  gemm_y<0>  <<<gemm_blocks, 256, 0, stream>>>(X2, Wt3, soutF, Yb);
  gather_y<0><<<gath_blocks, 256, 0, stream>>>(Yb, csr, row_ptr, sinF, bs3, H3);

  // Pool + head
  pool_kernel<<<256, 256, 0, stream>>>(H3, wout, hg);
  head_kernel<<<1, 64, 0, stream>>>(hg, Wlin, blin, out);
}